// Round 5
// baseline (5891.958 us; speedup 1.0000x reference)
//
#include <hip/hip_runtime.h>
#include <hip/hip_bf16.h>
#include <stdint.h>
#include <stddef.h>

// Problem dims: B=1024, T=512, F=8, E=16, H=32, O=1, TO=24

#define LOG2E 1.44269504088896340736f

__device__ __forceinline__ float fast_sigmoid(float x){
    return __builtin_amdgcn_rcpf(1.f + __builtin_amdgcn_exp2f(-LOG2E * x));
}
__device__ __forceinline__ float fast_tanh(float x){
    return 1.f - 2.f * __builtin_amdgcn_rcpf(1.f + __builtin_amdgcn_exp2f(2.f * LOG2E * x));
}
__device__ __forceinline__ float bflo(unsigned u){ return __uint_as_float(u << 16); }
__device__ __forceinline__ float bfhi(unsigned u){ return __uint_as_float(u & 0xffff0000u); }
__device__ __forceinline__ float bperm(int addr, float v){
    return __int_as_float(__builtin_amdgcn_ds_bpermute(addr, __float_as_int(v)));
}

// Device-scope one-shot grid barrier. ctr must be 0 before first use; each
// barrier slot is used exactly once per kernel launch. Release fence flushes
// this block's plain stores to the coherent point; acquire load + implicit
// invalidate makes other blocks' stores visible. NB = grid size (256).
__device__ __forceinline__ void gbar(unsigned* ctr){
    __syncthreads();
    if (threadIdx.x == 0){
        __threadfence();                 // agent-scope release (L2 writeback)
        atomicAdd(ctr, 1u);              // device-scope by default
        while (__hip_atomic_load(ctr, __ATOMIC_ACQUIRE, __HIP_MEMORY_SCOPE_AGENT) < 256u){
            __builtin_amdgcn_s_sleep(2);
        }
        __builtin_amdgcn_fence(__ATOMIC_ACQUIRE, "agent");
    }
    __syncthreads();
}

// ---------------------------------------------------------------------------
// Encoder: bidirectional GRU, ONE WAVE per sequence (64 lanes). (R3 version,
// verified: 254 µs, VALUBusy 84%.) Batched ds_read_b128 broadcasts + R0's
// ds_bpermute half-combine; accumulation chain order identical to R0.
// grid 512 x 256 (4 seqs/block, 2048 waves = 2 waves/SIMD).
// ---------------------------------------------------------------------------
__global__ __launch_bounds__(256, 2) void enc_kernel(
    const float* __restrict__ x,
    const float* __restrict__ emb_w, const float* __restrict__ emb_b,
    const float* __restrict__ wih_f, const float* __restrict__ whh_f,
    const float* __restrict__ bih_f, const float* __restrict__ bhh_f,
    const float* __restrict__ wih_b, const float* __restrict__ whh_b,
    const float* __restrict__ bih_b, const float* __restrict__ bhh_b,
    __hip_bfloat16* __restrict__ enc_outT, float* __restrict__ hT)
{
    __shared__ float lme[4][16];
    __shared__ float lh[4][32];

    int tid = threadIdx.x;
    int l = tid & 63;
    int wv = tid >> 6;
    int j = l & 31;
    int p = l >> 5;
    int S = blockIdx.x * 4 + wv;        // 0..2047
    int dir = S >> 10;
    int b = S & 1023;
    const float* wih = dir ? wih_b : wih_f;
    const float* whh = dir ? whh_b : whh_f;
    const float* bih = dir ? bih_b : bih_f;
    const float* bhh = dir ? bhh_b : bhh_f;

    // input-gate weights: e in [8p, 8p+8)
    float wr[8], wz[8], wn[8];
#pragma unroll
    for (int e = 0; e < 8; e++){
        int ee = 8 * p + e;
        wr[e] = wih[j * 16 + ee];
        wz[e] = wih[(32 + j) * 16 + ee];
        wn[e] = wih[(64 + j) * 16 + ee];
    }
    // hidden-gate weights: k in [16p, 16p+16)
    float ur[16], uz[16], un[16];
#pragma unroll
    for (int k = 0; k < 16; k++){
        int kk = 16 * p + k;
        ur[k] = whh[j * 32 + kk];
        uz[k] = whh[(32 + j) * 32 + kk];
        un[k] = whh[(64 + j) * 32 + kk];
    }
    // biases folded into p==0 lane's accumulator init (counted once after combine)
    float c_r  = p ? 0.f : (bih[j] + bhh[j]);
    float c_z  = p ? 0.f : (bih[32 + j] + bhh[32 + j]);
    float c_ni = p ? 0.f : bih[64 + j];
    float c_nh = p ? 0.f : bhh[64 + j];

    float ew[8];
#pragma unroll
    for (int f = 0; f < 8; f++) ew[f] = emb_w[(l & 15) * 8 + f];
    float ebias = emb_b[l & 15];

    int aX = 4 * (l ^ 32);   // bpermute byte address for the half-combine

    float h = 0.f;
    const float* xp = x + (size_t)b * 4096 + (dir ? 511 * 8 : 0);
    __hip_bfloat16* op = enc_outT + ((size_t)b * 512 + (dir ? 511 : 0)) * 64 + dir * 32 + j;
    int xstep = dir ? -8 : 8;
    ptrdiff_t ostep = dir ? -64 : 64;

    float4 cx0 = ((const float4*)xp)[0];
    float4 cx1 = ((const float4*)xp)[1];

    // me for t=0
    float me;
    {
        float e0 = ebias;
        e0 = fmaf(cx0.x, ew[0], e0); e0 = fmaf(cx0.y, ew[1], e0);
        e0 = fmaf(cx0.z, ew[2], e0); e0 = fmaf(cx0.w, ew[3], e0);
        e0 = fmaf(cx1.x, ew[4], e0); e0 = fmaf(cx1.y, ew[5], e0);
        e0 = fmaf(cx1.z, ew[6], e0); e0 = fmaf(cx1.w, ew[7], e0);
        me = fmaxf(e0, 0.f);
    }
    if (l < 16) lme[wv][l] = me;   // lanes 0..15 hold me[0..15]
    if (l < 32) lh[wv][l] = h;     // p0 half holds h[0..31]

    const float4* pe = (const float4*)(&lme[wv][8 * p]);
    const float4* ph = (const float4*)(&lh[wv][16 * p]);

    for (int it = 0; it < 512; ++it){
        // prefetch next x (clamped on last iter)
        const float* np = (it == 511) ? xp : (xp + xstep);
        float4 nx0 = ((const float4*)np)[0];
        float4 nx1 = ((const float4*)np)[1];

        // batched LDS broadcast reads (one DS latency for all six)
        float4 e01 = pe[0], e23 = pe[1];
        float4 h0 = ph[0], h1 = ph[1], h2 = ph[2], h3 = ph[3];

        // gate accumulators — SAME chain order as the verified R0 kernel:
        // bias, then e[0..7], then h[0..15], single chain each.
        float Ar = c_r, Az = c_z, Ani = c_ni, Anh = c_nh;

        Ar = fmaf(e01.x, wr[0], Ar); Az = fmaf(e01.x, wz[0], Az); Ani = fmaf(e01.x, wn[0], Ani);
        Ar = fmaf(e01.y, wr[1], Ar); Az = fmaf(e01.y, wz[1], Az); Ani = fmaf(e01.y, wn[1], Ani);
        Ar = fmaf(e01.z, wr[2], Ar); Az = fmaf(e01.z, wz[2], Az); Ani = fmaf(e01.z, wn[2], Ani);
        Ar = fmaf(e01.w, wr[3], Ar); Az = fmaf(e01.w, wz[3], Az); Ani = fmaf(e01.w, wn[3], Ani);
        Ar = fmaf(e23.x, wr[4], Ar); Az = fmaf(e23.x, wz[4], Az); Ani = fmaf(e23.x, wn[4], Ani);
        Ar = fmaf(e23.y, wr[5], Ar); Az = fmaf(e23.y, wz[5], Az); Ani = fmaf(e23.y, wn[5], Ani);
        Ar = fmaf(e23.z, wr[6], Ar); Az = fmaf(e23.z, wz[6], Az); Ani = fmaf(e23.z, wn[6], Ani);
        Ar = fmaf(e23.w, wr[7], Ar); Az = fmaf(e23.w, wz[7], Az); Ani = fmaf(e23.w, wn[7], Ani);

        Ar = fmaf(h0.x, ur[0], Ar);  Az = fmaf(h0.x, uz[0], Az);  Anh = fmaf(h0.x, un[0], Anh);
        Ar = fmaf(h0.y, ur[1], Ar);  Az = fmaf(h0.y, uz[1], Az);  Anh = fmaf(h0.y, un[1], Anh);
        Ar = fmaf(h0.z, ur[2], Ar);  Az = fmaf(h0.z, uz[2], Az);  Anh = fmaf(h0.z, un[2], Anh);
        Ar = fmaf(h0.w, ur[3], Ar);  Az = fmaf(h0.w, uz[3], Az);  Anh = fmaf(h0.w, un[3], Anh);
        Ar = fmaf(h1.x, ur[4], Ar);  Az = fmaf(h1.x, uz[4], Az);  Anh = fmaf(h1.x, un[4], Anh);
        Ar = fmaf(h1.y, ur[5], Ar);  Az = fmaf(h1.y, uz[5], Az);  Anh = fmaf(h1.y, un[5], Anh);
        Ar = fmaf(h1.z, ur[6], Ar);  Az = fmaf(h1.z, uz[6], Az);  Anh = fmaf(h1.z, un[6], Anh);
        Ar = fmaf(h1.w, ur[7], Ar);  Az = fmaf(h1.w, uz[7], Az);  Anh = fmaf(h1.w, un[7], Anh);
        Ar = fmaf(h2.x, ur[8], Ar);  Az = fmaf(h2.x, uz[8], Az);  Anh = fmaf(h2.x, un[8], Anh);
        Ar = fmaf(h2.y, ur[9], Ar);  Az = fmaf(h2.y, uz[9], Az);  Anh = fmaf(h2.y, un[9], Anh);
        Ar = fmaf(h2.z, ur[10], Ar); Az = fmaf(h2.z, uz[10], Az); Anh = fmaf(h2.z, un[10], Anh);
        Ar = fmaf(h2.w, ur[11], Ar); Az = fmaf(h2.w, uz[11], Az); Anh = fmaf(h2.w, un[11], Anh);
        Ar = fmaf(h3.x, ur[12], Ar); Az = fmaf(h3.x, uz[12], Az); Anh = fmaf(h3.x, un[12], Anh);
        Ar = fmaf(h3.y, ur[13], Ar); Az = fmaf(h3.y, uz[13], Az); Anh = fmaf(h3.y, un[13], Anh);
        Ar = fmaf(h3.z, ur[14], Ar); Az = fmaf(h3.z, uz[14], Az); Anh = fmaf(h3.z, un[14], Anh);
        Ar = fmaf(h3.w, ur[15], Ar); Az = fmaf(h3.w, uz[15], Az); Anh = fmaf(h3.w, un[15], Anh);

        // combine p-halves exactly as R0 (ds_bpermute l^32), batched.
        float tr  = bperm(aX, Ar);
        float tz  = bperm(aX, Az);
        float tni = bperm(aX, Ani);
        float tnh = bperm(aX, Anh);
        Ar  += tr;
        Az  += tz;
        Ani += tni;
        Anh += tnh;

        float r = fast_sigmoid(Ar);
        float z = fast_sigmoid(Az);
        float cand = fast_tanh(fmaf(r, Anh, Ani));
        h = (1.f - z) * cand + z * h;

        if (l < 32) lh[wv][l] = h;          // publish h for next step ASAP
        *op = __float2bfloat16(h);          // both halves write same value: ok

        // me for next step from prefetched x (independent of h-chain)
        float e0 = ebias;
        e0 = fmaf(nx0.x, ew[0], e0); e0 = fmaf(nx0.y, ew[1], e0);
        e0 = fmaf(nx0.z, ew[2], e0); e0 = fmaf(nx0.w, ew[3], e0);
        e0 = fmaf(nx1.x, ew[4], e0); e0 = fmaf(nx1.y, ew[5], e0);
        e0 = fmaf(nx1.z, ew[6], e0); e0 = fmaf(nx1.w, ew[7], e0);
        me = fmaxf(e0, 0.f);
        if (l < 16) lme[wv][l] = me;

        xp = np; op += ostep;
    }
    hT[b * 64 + dir * 32 + j] = h;
}

// ---------------------------------------------------------------------------
// s0 = tanh([hTf,hTb] @ act_w^T + act_b); sWs0 = s0 @ Ws^T; dec_in0 = x[:,511,0].
// Also zeroes the 48 grid-barrier counters (block 0). grid 128 x 256.
// ---------------------------------------------------------------------------
__global__ __launch_bounds__(256) void s0_kernel(
    const float* __restrict__ hT, const float* __restrict__ act_w, const float* __restrict__ act_b,
    const float* __restrict__ attn_w, const float* __restrict__ x,
    float* __restrict__ s, float* __restrict__ sWs, float* __restrict__ dec_in,
    unsigned* __restrict__ bar)
{
    if (blockIdx.x == 0 && threadIdx.x < 48) bar[threadIdx.x] = 0u;
    int j = threadIdx.x & 31, g = threadIdx.x >> 5;
    int b = blockIdx.x * 8 + g;
    float acc = act_b[j];
    const float4* aw = (const float4*)(act_w + j * 64);
    const float4* hp = (const float4*)(hT + b * 64);
#pragma unroll
    for (int c = 0; c < 16; c++){
        float4 wv = aw[c]; float4 hv = hp[c];
        acc = fmaf(hv.x, wv.x, acc); acc = fmaf(hv.y, wv.y, acc);
        acc = fmaf(hv.z, wv.z, acc); acc = fmaf(hv.w, wv.w, acc);
    }
    float s0v = fast_tanh(acc);
    s[b * 32 + j] = s0v;
    __shared__ float ssh[8][33];
    ssh[g][j] = s0v;
    __syncthreads();
    float a = 0.f;
    const float4* wsp = (const float4*)(attn_w + j * 96);   // Ws = attn_w[:, :32]
#pragma unroll
    for (int c = 0; c < 8; c++){
        float4 wv = wsp[c];
        a = fmaf(ssh[g][4 * c + 0], wv.x, a);
        a = fmaf(ssh[g][4 * c + 1], wv.y, a);
        a = fmaf(ssh[g][4 * c + 2], wv.z, a);
        a = fmaf(ssh[g][4 * c + 3], wv.w, a);
    }
    sWs[b * 32 + j] = a;
    if (j == 0) dec_in[b] = x[(size_t)b * 4096 + 511 * 8];
}

// ---------------------------------------------------------------------------
// enc_proj[t,b,j] = sum_d enc_outT[b,t,d] * We[j,d];  We = attn_w[:, 32:96]
// Reads enc_outT rows ([b][t][64] contiguous), writes proj in [t][b][32].
// grid 2048 x 256.
// ---------------------------------------------------------------------------
__global__ __launch_bounds__(256) void proj_kernel(
    const __hip_bfloat16* __restrict__ enc_outT, const float* __restrict__ attn_w,
    __hip_bfloat16* __restrict__ proj)
{
    int j = threadIdx.x & 31, g = threadIdx.x >> 5;
    float w[64];
    const float4* aw = (const float4*)(attn_w + j * 96 + 32);
#pragma unroll
    for (int c = 0; c < 16; c++){
        float4 q = aw[c];
        w[4 * c] = q.x; w[4 * c + 1] = q.y; w[4 * c + 2] = q.z; w[4 * c + 3] = q.w;
    }
    size_t base = (size_t)blockIdx.x * 256 + g * 32;
    for (int r = 0; r < 32; ++r){
        size_t pl = base + r;                      // pl = b*512 + t
        const uint4* ev = (const uint4*)(enc_outT + pl * 64);
        float acc = 0.f;
#pragma unroll
        for (int c = 0; c < 8; c++){
            uint4 pk = ev[c];
            acc = fmaf(bflo(pk.x), w[8 * c + 0], acc);
            acc = fmaf(bfhi(pk.x), w[8 * c + 1], acc);
            acc = fmaf(bflo(pk.y), w[8 * c + 2], acc);
            acc = fmaf(bfhi(pk.y), w[8 * c + 3], acc);
            acc = fmaf(bflo(pk.z), w[8 * c + 4], acc);
            acc = fmaf(bfhi(pk.z), w[8 * c + 5], acc);
            acc = fmaf(bflo(pk.w), w[8 * c + 6], acc);
            acc = fmaf(bfhi(pk.w), w[8 * c + 7], acc);
        }
        int t = (int)(pl & 511);
        int bb = (int)(pl >> 9);
        proj[((size_t)t * 1024 + bb) * 32 + j] = __float2bfloat16(acc);
    }
}

// ---------------------------------------------------------------------------
// Fused 24-step decode, persistent kernel with hand-rolled device barriers.
// grid 256 x 256 (<= 1 block/CU: co-residency unconditional; deadlock-proof).
// Per step:
//   Phase A: block owns t in {bid, bid+256}; 4 b's per thread. E[t,b] ->
//     Ebuf (coalesced row), block tree-reduce -> denom[t] (plain store; this
//     block is the only writer — no atomics, no pre-zeroing).
//   gbar
//   Phase B: block owns b in {bid, bid+256, bid+512, bid+768} sequentially.
//     Softmax weights from Ebuf column + denom, ctx sweep over enc_outT[b],
//     GRU, fc -> out; s and dec_in persist in LDS (scur4/dins4).
//   gbar
// Arithmetic per (t,b)/per b is op-for-op the verified split kernels; only
// the denom summation grouping changes (tree vs atomic order, ~1e-7 rel).
// ---------------------------------------------------------------------------
__global__ __launch_bounds__(256, 2) void dec_persist(
    const __hip_bfloat16* __restrict__ enc_outT, const __hip_bfloat16* __restrict__ proj,
    const float* __restrict__ s_init, float* __restrict__ sWs,
    const float* __restrict__ dec_in_init, float* __restrict__ Ebuf,
    float* __restrict__ denom, unsigned* __restrict__ bar,
    const float* __restrict__ attn_v,
    const float* __restrict__ demb_w, const float* __restrict__ demb_b,
    const float* __restrict__ dwih, const float* __restrict__ dwhh,
    const float* __restrict__ dbih, const float* __restrict__ dbhh,
    const float* __restrict__ attn_w, const float* __restrict__ fc_w,
    const float* __restrict__ fc_b, float* __restrict__ out)
{
    __shared__ float w_sh[512];
    __shared__ float ctxp[4][64];
    __shared__ float rnn_sh[80];    // [embd(16), ctx(64)]
    __shared__ float scur4[4][32];  // persistent hidden state, 4 b's
    __shared__ float gsum[64];
    __shared__ float gin[32], ghn[32];
    __shared__ float snew[32];
    __shared__ float wsum[4];
    __shared__ float dins4[4];      // persistent dec_in, 4 b's

    int tid = threadIdx.x;
    int bid = blockIdx.x;
    int wv = tid >> 6, l = tid & 63;

    // attention v vector, registers for the whole loop
    float v[32];
    {
        const float4* vv = (const float4*)attn_v;
#pragma unroll
        for (int c = 0; c < 8; c++){
            float4 q = vv[c];
            v[4 * c] = q.x; v[4 * c + 1] = q.y; v[4 * c + 2] = q.z; v[4 * c + 3] = q.w;
        }
    }

    // persistent per-b state init
    if (tid < 32){
#pragma unroll
        for (int k = 0; k < 4; k++) scur4[k][tid] = s_init[(bid + 256 * k) * 32 + tid];
    }
    if (tid == 0){
#pragma unroll
        for (int k = 0; k < 4; k++) dins4[k] = dec_in_init[bid + 256 * k];
    }
    __syncthreads();

    for (int st = 0; st < 24; ++st){
        // ---------------- Phase A: scores + denom for t = bid, bid+256 ----
#pragma unroll
        for (int half = 0; half < 2; ++half){
            int t = bid + 256 * half;
            float partial = 0.f;
#pragma unroll
            for (int q = 0; q < 4; ++q){
                int b = tid + 256 * q;
                const uint4* pp = (const uint4*)(proj + ((size_t)t * 1024 + b) * 32);
                const float4* sp = (const float4*)(sWs + b * 32);
                float acc = 0.f;
#pragma unroll
                for (int c = 0; c < 4; c++){
                    uint4 pk = pp[c];
                    float4 s0 = sp[2 * c], s1 = sp[2 * c + 1];
                    acc = fmaf(v[8 * c + 0], fast_tanh(s0.x + bflo(pk.x)), acc);
                    acc = fmaf(v[8 * c + 1], fast_tanh(s0.y + bfhi(pk.x)), acc);
                    acc = fmaf(v[8 * c + 2], fast_tanh(s0.z + bflo(pk.y)), acc);
                    acc = fmaf(v[8 * c + 3], fast_tanh(s0.w + bfhi(pk.y)), acc);
                    acc = fmaf(v[8 * c + 4], fast_tanh(s1.x + bflo(pk.z)), acc);
                    acc = fmaf(v[8 * c + 5], fast_tanh(s1.y + bfhi(pk.z)), acc);
                    acc = fmaf(v[8 * c + 6], fast_tanh(s1.z + bflo(pk.w)), acc);
                    acc = fmaf(v[8 * c + 7], fast_tanh(s1.w + bfhi(pk.w)), acc);
                }
                float Ev = __builtin_amdgcn_exp2f(LOG2E * acc);
                Ebuf[(size_t)t * 1024 + b] = Ev;
                partial += Ev;
            }
#pragma unroll
            for (int o = 32; o >= 1; o >>= 1) partial += __shfl_xor(partial, o, 64);
            if (l == 0) wsum[wv] = partial;
            __syncthreads();
            if (tid == 0) denom[t] = wsum[0] + wsum[1] + wsum[2] + wsum[3];
            __syncthreads();   // wsum reused by half=1
        }

        gbar(bar + 2 * st);

        // ---------------- Phase B: decoder step for 4 b's -----------------
#pragma unroll 1
        for (int k = 0; k < 4; ++k){
            int b = bid + 256 * k;
            {
                float d0 = denom[tid], d1 = denom[tid + 256];
                float e0 = Ebuf[(size_t)tid * 1024 + b];
                float e1 = Ebuf[(size_t)(tid + 256) * 1024 + b];
                w_sh[tid] = e0 * __builtin_amdgcn_rcpf(d0);
                w_sh[tid + 256] = e1 * __builtin_amdgcn_rcpf(d1);
            }
            if (tid < 16) rnn_sh[tid] = fmaxf(fmaf(dins4[k], demb_w[tid], demb_b[tid]), 0.f);
            __syncthreads();

            // ctx: contiguous 64KB sweep; thread = d-octet (tid&7), t = i*32+(tid>>3)
            {
                float acc0 = 0.f, acc1 = 0.f, acc2 = 0.f, acc3 = 0.f;
                float acc4 = 0.f, acc5 = 0.f, acc6 = 0.f, acc7 = 0.f;
                const uint4* ep = (const uint4*)(enc_outT + (size_t)b * 32768);
#pragma unroll
                for (int i = 0; i < 16; i++){
                    int idx = i * 256 + tid;
                    uint4 pk = ep[idx];
                    float wgt = w_sh[idx >> 3];
                    acc0 = fmaf(wgt, bflo(pk.x), acc0);
                    acc1 = fmaf(wgt, bfhi(pk.x), acc1);
                    acc2 = fmaf(wgt, bflo(pk.y), acc2);
                    acc3 = fmaf(wgt, bfhi(pk.y), acc3);
                    acc4 = fmaf(wgt, bflo(pk.z), acc4);
                    acc5 = fmaf(wgt, bfhi(pk.z), acc5);
                    acc6 = fmaf(wgt, bflo(pk.w), acc6);
                    acc7 = fmaf(wgt, bfhi(pk.w), acc7);
                }
#pragma unroll
                for (int o = 8; o <= 32; o <<= 1){
                    acc0 += __shfl_xor(acc0, o, 64); acc1 += __shfl_xor(acc1, o, 64);
                    acc2 += __shfl_xor(acc2, o, 64); acc3 += __shfl_xor(acc3, o, 64);
                    acc4 += __shfl_xor(acc4, o, 64); acc5 += __shfl_xor(acc5, o, 64);
                    acc6 += __shfl_xor(acc6, o, 64); acc7 += __shfl_xor(acc7, o, 64);
                }
                if (l < 8){
                    float* cp = &ctxp[wv][l * 8];
                    cp[0] = acc0; cp[1] = acc1; cp[2] = acc2; cp[3] = acc3;
                    cp[4] = acc4; cp[5] = acc5; cp[6] = acc6; cp[7] = acc7;
                }
            }
            __syncthreads();
            if (tid < 64) rnn_sh[16 + tid] = ctxp[0][tid] + ctxp[1][tid] + ctxp[2][tid] + ctxp[3][tid];
            __syncthreads();

            if (tid < 96){
                int row = tid;
                float gi = dbih[row];
                const float4* wr = (const float4*)(dwih + row * 80);
#pragma unroll
                for (int c = 0; c < 20; c++){
                    float4 wv4 = wr[c];
                    gi = fmaf(rnn_sh[4 * c + 0], wv4.x, gi);
                    gi = fmaf(rnn_sh[4 * c + 1], wv4.y, gi);
                    gi = fmaf(rnn_sh[4 * c + 2], wv4.z, gi);
                    gi = fmaf(rnn_sh[4 * c + 3], wv4.w, gi);
                }
                float gh = dbhh[row];
                const float4* urow = (const float4*)(dwhh + row * 32);
#pragma unroll
                for (int c = 0; c < 8; c++){
                    float4 wv4 = urow[c];
                    gh = fmaf(scur4[k][4 * c + 0], wv4.x, gh);
                    gh = fmaf(scur4[k][4 * c + 1], wv4.y, gh);
                    gh = fmaf(scur4[k][4 * c + 2], wv4.z, gh);
                    gh = fmaf(scur4[k][4 * c + 3], wv4.w, gh);
                }
                if (row < 64) gsum[row] = gi + gh;
                else { gin[row - 64] = gi; ghn[row - 64] = gh; }
            }
            __syncthreads();

            if (tid < 32){
                float r = fast_sigmoid(gsum[tid]);
                float z = fast_sigmoid(gsum[32 + tid]);
                float cand = fast_tanh(fmaf(r, ghn[tid], gin[tid]));
                float sn = (1.f - z) * cand + z * scur4[k][tid];
                snew[tid] = sn;
                scur4[k][tid] = sn;
            }
            __syncthreads();

            if (tid < 32){   // next-step sWs (global: read by phase A)
                float a = 0.f;
                const float4* aw = (const float4*)(attn_w + tid * 96);
#pragma unroll
                for (int c = 0; c < 8; c++){
                    float4 wv4 = aw[c];
                    a = fmaf(snew[4 * c + 0], wv4.x, a);
                    a = fmaf(snew[4 * c + 1], wv4.y, a);
                    a = fmaf(snew[4 * c + 2], wv4.z, a);
                    a = fmaf(snew[4 * c + 3], wv4.w, a);
                }
                sWs[b * 32 + tid] = a;
            } else if (tid >= 64 && tid < 128){   // fc: pred = cat(112) . fc_w + fc_b
                int ll = tid - 64;
                float cv0 = (ll < 32) ? snew[ll] : rnn_sh[ll - 16];
                float p = cv0 * fc_w[ll];
                if (ll < 48){
                    int i = 64 + ll;
                    float cv1 = (i < 96) ? rnn_sh[i - 16] : rnn_sh[i - 96];
                    p = fmaf(cv1, fc_w[i], p);
                }
#pragma unroll
                for (int o = 32; o >= 1; o >>= 1) p += __shfl_xor(p, o, 64);
                if (ll == 0){
                    float pred = p + fc_b[0];
                    out[b * 24 + st] = pred;
                    dins4[k] = pred;
                }
            }
            __syncthreads();   // protect w_sh/rnn_sh before next k
        }

        gbar(bar + 2 * st + 1);
    }
}

// ---------------------------------------------------------------------------
extern "C" void kernel_launch(void* const* d_in, const int* in_sizes, int n_in,
                              void* d_out, int out_size, void* d_ws, size_t ws_size,
                              hipStream_t stream)
{
    const float* x      = (const float*)d_in[0];
    const float* emb_w  = (const float*)d_in[2];
    const float* emb_b  = (const float*)d_in[3];
    const float* wih_f  = (const float*)d_in[4];
    const float* whh_f  = (const float*)d_in[5];
    const float* bih_f  = (const float*)d_in[6];
    const float* bhh_f  = (const float*)d_in[7];
    const float* wih_b  = (const float*)d_in[8];
    const float* whh_b  = (const float*)d_in[9];
    const float* bih_b  = (const float*)d_in[10];
    const float* bhh_b  = (const float*)d_in[11];
    const float* act_w  = (const float*)d_in[12];
    const float* act_b  = (const float*)d_in[13];
    const float* attn_w = (const float*)d_in[14];
    const float* attn_v = (const float*)d_in[15];
    const float* demb_w = (const float*)d_in[16];
    const float* demb_b = (const float*)d_in[17];
    const float* dwih   = (const float*)d_in[18];
    const float* dwhh   = (const float*)d_in[19];
    const float* dbih   = (const float*)d_in[20];
    const float* dbhh   = (const float*)d_in[21];
    const float* fc_w   = (const float*)d_in[22];
    const float* fc_b   = (const float*)d_in[23];
    (void)in_sizes; (void)n_in; (void)out_size; (void)ws_size;

    char* w = (char*)d_ws;
    __hip_bfloat16* enc_outT = (__hip_bfloat16*)w;                // [b][t][64] bf16, 67108864 B
    __hip_bfloat16* proj     = (__hip_bfloat16*)(w + 67108864);   // [t][b][32] bf16, 33554432 B
    float* hT     = (float*)(w + 100663296);                      // 1024*64*4
    float* s      = (float*)(w + 100925440);                      // 1024*32*4
    float* sWs    = (float*)(w + 101056512);                      // 1024*32*4
    float* Ebuf   = (float*)(w + 101187584);                      // [t][b] f32, 2097152 B
    float* denom  = (float*)(w + 103284736);                      // 512*4
    unsigned* bar = (unsigned*)(w + 103286784);                   // 48*4 barrier counters
    float* dec_in = (float*)(w + 103333888);                      // 1024*4
    float* out = (float*)d_out;

    enc_kernel<<<512, 256, 0, stream>>>(x, emb_w, emb_b, wih_f, whh_f, bih_f, bhh_f,
                                        wih_b, whh_b, bih_b, bhh_b, enc_outT, hT);
    s0_kernel<<<128, 256, 0, stream>>>(hT, act_w, act_b, attn_w, x, s, sWs, dec_in, bar);
    proj_kernel<<<2048, 256, 0, stream>>>(enc_outT, attn_w, proj);
    dec_persist<<<256, 256, 0, stream>>>(enc_outT, proj, s, sWs, dec_in, Ebuf, denom, bar,
                                         attn_v, demb_w, demb_b, dwih, dwhh, dbih, dbhh,
                                         attn_w, fc_w, fc_b, out);
}

// Round 6
// 4767.345 us; speedup vs baseline: 1.2359x; 1.2359x over previous
//
#include <hip/hip_runtime.h>
#include <hip/hip_bf16.h>
#include <stdint.h>
#include <stddef.h>

// Problem dims: B=1024, T=512, F=8, E=16, H=32, O=1, TO=24

#define LOG2E 1.44269504088896340736f

__device__ __forceinline__ float fast_sigmoid(float x){
    return __builtin_amdgcn_rcpf(1.f + __builtin_amdgcn_exp2f(-LOG2E * x));
}
__device__ __forceinline__ float fast_tanh(float x){
    return 1.f - 2.f * __builtin_amdgcn_rcpf(1.f + __builtin_amdgcn_exp2f(2.f * LOG2E * x));
}
__device__ __forceinline__ float bflo(unsigned u){ return __uint_as_float(u << 16); }
__device__ __forceinline__ float bfhi(unsigned u){ return __uint_as_float(u & 0xffff0000u); }
__device__ __forceinline__ float bperm(int addr, float v){
    return __int_as_float(__builtin_amdgcn_ds_bpermute(addr, __float_as_int(v)));
}

// Device-scope one-shot grid barrier (proven in R5). ctr zeroed by s0_kernel.
// NB = grid size (512 now).
__device__ __forceinline__ void gbar(unsigned* ctr){
    __syncthreads();
    if (threadIdx.x == 0){
        __threadfence();
        atomicAdd(ctr, 1u);
        while (__hip_atomic_load(ctr, __ATOMIC_ACQUIRE, __HIP_MEMORY_SCOPE_AGENT) < 512u){
            __builtin_amdgcn_s_sleep(2);
        }
        __builtin_amdgcn_fence(__ATOMIC_ACQUIRE, "agent");
    }
    __syncthreads();
}

// ---------------------------------------------------------------------------
// Encoder: bidirectional GRU, ONE WAVE per sequence. (R3 verified: 254 µs.)
// ---------------------------------------------------------------------------
__global__ __launch_bounds__(256, 2) void enc_kernel(
    const float* __restrict__ x,
    const float* __restrict__ emb_w, const float* __restrict__ emb_b,
    const float* __restrict__ wih_f, const float* __restrict__ whh_f,
    const float* __restrict__ bih_f, const float* __restrict__ bhh_f,
    const float* __restrict__ wih_b, const float* __restrict__ whh_b,
    const float* __restrict__ bih_b, const float* __restrict__ bhh_b,
    __hip_bfloat16* __restrict__ enc_outT, float* __restrict__ hT)
{
    __shared__ float lme[4][16];
    __shared__ float lh[4][32];

    int tid = threadIdx.x;
    int l = tid & 63;
    int wv = tid >> 6;
    int j = l & 31;
    int p = l >> 5;
    int S = blockIdx.x * 4 + wv;        // 0..2047
    int dir = S >> 10;
    int b = S & 1023;
    const float* wih = dir ? wih_b : wih_f;
    const float* whh = dir ? whh_b : whh_f;
    const float* bih = dir ? bih_b : bih_f;
    const float* bhh = dir ? bhh_b : bhh_f;

    float wr[8], wz[8], wn[8];
#pragma unroll
    for (int e = 0; e < 8; e++){
        int ee = 8 * p + e;
        wr[e] = wih[j * 16 + ee];
        wz[e] = wih[(32 + j) * 16 + ee];
        wn[e] = wih[(64 + j) * 16 + ee];
    }
    float ur[16], uz[16], un[16];
#pragma unroll
    for (int k = 0; k < 16; k++){
        int kk = 16 * p + k;
        ur[k] = whh[j * 32 + kk];
        uz[k] = whh[(32 + j) * 32 + kk];
        un[k] = whh[(64 + j) * 32 + kk];
    }
    float c_r  = p ? 0.f : (bih[j] + bhh[j]);
    float c_z  = p ? 0.f : (bih[32 + j] + bhh[32 + j]);
    float c_ni = p ? 0.f : bih[64 + j];
    float c_nh = p ? 0.f : bhh[64 + j];

    float ew[8];
#pragma unroll
    for (int f = 0; f < 8; f++) ew[f] = emb_w[(l & 15) * 8 + f];
    float ebias = emb_b[l & 15];

    int aX = 4 * (l ^ 32);

    float h = 0.f;
    const float* xp = x + (size_t)b * 4096 + (dir ? 511 * 8 : 0);
    __hip_bfloat16* op = enc_outT + ((size_t)b * 512 + (dir ? 511 : 0)) * 64 + dir * 32 + j;
    int xstep = dir ? -8 : 8;
    ptrdiff_t ostep = dir ? -64 : 64;

    float4 cx0 = ((const float4*)xp)[0];
    float4 cx1 = ((const float4*)xp)[1];

    float me;
    {
        float e0 = ebias;
        e0 = fmaf(cx0.x, ew[0], e0); e0 = fmaf(cx0.y, ew[1], e0);
        e0 = fmaf(cx0.z, ew[2], e0); e0 = fmaf(cx0.w, ew[3], e0);
        e0 = fmaf(cx1.x, ew[4], e0); e0 = fmaf(cx1.y, ew[5], e0);
        e0 = fmaf(cx1.z, ew[6], e0); e0 = fmaf(cx1.w, ew[7], e0);
        me = fmaxf(e0, 0.f);
    }
    if (l < 16) lme[wv][l] = me;
    if (l < 32) lh[wv][l] = h;

    const float4* pe = (const float4*)(&lme[wv][8 * p]);
    const float4* ph = (const float4*)(&lh[wv][16 * p]);

    for (int it = 0; it < 512; ++it){
        const float* np = (it == 511) ? xp : (xp + xstep);
        float4 nx0 = ((const float4*)np)[0];
        float4 nx1 = ((const float4*)np)[1];

        float4 e01 = pe[0], e23 = pe[1];
        float4 h0 = ph[0], h1 = ph[1], h2 = ph[2], h3 = ph[3];

        float Ar = c_r, Az = c_z, Ani = c_ni, Anh = c_nh;

        Ar = fmaf(e01.x, wr[0], Ar); Az = fmaf(e01.x, wz[0], Az); Ani = fmaf(e01.x, wn[0], Ani);
        Ar = fmaf(e01.y, wr[1], Ar); Az = fmaf(e01.y, wz[1], Az); Ani = fmaf(e01.y, wn[1], Ani);
        Ar = fmaf(e01.z, wr[2], Ar); Az = fmaf(e01.z, wz[2], Az); Ani = fmaf(e01.z, wn[2], Ani);
        Ar = fmaf(e01.w, wr[3], Ar); Az = fmaf(e01.w, wz[3], Az); Ani = fmaf(e01.w, wn[3], Ani);
        Ar = fmaf(e23.x, wr[4], Ar); Az = fmaf(e23.x, wz[4], Az); Ani = fmaf(e23.x, wn[4], Ani);
        Ar = fmaf(e23.y, wr[5], Ar); Az = fmaf(e23.y, wz[5], Az); Ani = fmaf(e23.y, wn[5], Ani);
        Ar = fmaf(e23.z, wr[6], Ar); Az = fmaf(e23.z, wz[6], Az); Ani = fmaf(e23.z, wn[6], Ani);
        Ar = fmaf(e23.w, wr[7], Ar); Az = fmaf(e23.w, wz[7], Az); Ani = fmaf(e23.w, wn[7], Ani);

        Ar = fmaf(h0.x, ur[0], Ar);  Az = fmaf(h0.x, uz[0], Az);  Anh = fmaf(h0.x, un[0], Anh);
        Ar = fmaf(h0.y, ur[1], Ar);  Az = fmaf(h0.y, uz[1], Az);  Anh = fmaf(h0.y, un[1], Anh);
        Ar = fmaf(h0.z, ur[2], Ar);  Az = fmaf(h0.z, uz[2], Az);  Anh = fmaf(h0.z, un[2], Anh);
        Ar = fmaf(h0.w, ur[3], Ar);  Az = fmaf(h0.w, uz[3], Az);  Anh = fmaf(h0.w, un[3], Anh);
        Ar = fmaf(h1.x, ur[4], Ar);  Az = fmaf(h1.x, uz[4], Az);  Anh = fmaf(h1.x, un[4], Anh);
        Ar = fmaf(h1.y, ur[5], Ar);  Az = fmaf(h1.y, uz[5], Az);  Anh = fmaf(h1.y, un[5], Anh);
        Ar = fmaf(h1.z, ur[6], Ar);  Az = fmaf(h1.z, uz[6], Az);  Anh = fmaf(h1.z, un[6], Anh);
        Ar = fmaf(h1.w, ur[7], Ar);  Az = fmaf(h1.w, uz[7], Az);  Anh = fmaf(h1.w, un[7], Anh);
        Ar = fmaf(h2.x, ur[8], Ar);  Az = fmaf(h2.x, uz[8], Az);  Anh = fmaf(h2.x, un[8], Anh);
        Ar = fmaf(h2.y, ur[9], Ar);  Az = fmaf(h2.y, uz[9], Az);  Anh = fmaf(h2.y, un[9], Anh);
        Ar = fmaf(h2.z, ur[10], Ar); Az = fmaf(h2.z, uz[10], Az); Anh = fmaf(h2.z, un[10], Anh);
        Ar = fmaf(h2.w, ur[11], Ar); Az = fmaf(h2.w, uz[11], Az); Anh = fmaf(h2.w, un[11], Anh);
        Ar = fmaf(h3.x, ur[12], Ar); Az = fmaf(h3.x, uz[12], Az); Anh = fmaf(h3.x, un[12], Anh);
        Ar = fmaf(h3.y, ur[13], Ar); Az = fmaf(h3.y, uz[13], Az); Anh = fmaf(h3.y, un[13], Anh);
        Ar = fmaf(h3.z, ur[14], Ar); Az = fmaf(h3.z, uz[14], Az); Anh = fmaf(h3.z, un[14], Anh);
        Ar = fmaf(h3.w, ur[15], Ar); Az = fmaf(h3.w, uz[15], Az); Anh = fmaf(h3.w, un[15], Anh);

        float tr  = bperm(aX, Ar);
        float tz  = bperm(aX, Az);
        float tni = bperm(aX, Ani);
        float tnh = bperm(aX, Anh);
        Ar  += tr;
        Az  += tz;
        Ani += tni;
        Anh += tnh;

        float r = fast_sigmoid(Ar);
        float z = fast_sigmoid(Az);
        float cand = fast_tanh(fmaf(r, Anh, Ani));
        h = (1.f - z) * cand + z * h;

        if (l < 32) lh[wv][l] = h;
        *op = __float2bfloat16(h);

        float e0 = ebias;
        e0 = fmaf(nx0.x, ew[0], e0); e0 = fmaf(nx0.y, ew[1], e0);
        e0 = fmaf(nx0.z, ew[2], e0); e0 = fmaf(nx0.w, ew[3], e0);
        e0 = fmaf(nx1.x, ew[4], e0); e0 = fmaf(nx1.y, ew[5], e0);
        e0 = fmaf(nx1.z, ew[6], e0); e0 = fmaf(nx1.w, ew[7], e0);
        me = fmaxf(e0, 0.f);
        if (l < 16) lme[wv][l] = me;

        xp = np; op += ostep;
    }
    hT[b * 64 + dir * 32 + j] = h;
}

// ---------------------------------------------------------------------------
// s0 kernel (verified) + zeroes 48 grid-barrier counters. grid 128 x 256.
// ---------------------------------------------------------------------------
__global__ __launch_bounds__(256) void s0_kernel(
    const float* __restrict__ hT, const float* __restrict__ act_w, const float* __restrict__ act_b,
    const float* __restrict__ attn_w, const float* __restrict__ x,
    float* __restrict__ s, float* __restrict__ sWs, float* __restrict__ dec_in,
    unsigned* __restrict__ bar)
{
    if (blockIdx.x == 0 && threadIdx.x < 48) bar[threadIdx.x] = 0u;
    int j = threadIdx.x & 31, g = threadIdx.x >> 5;
    int b = blockIdx.x * 8 + g;
    float acc = act_b[j];
    const float4* aw = (const float4*)(act_w + j * 64);
    const float4* hp = (const float4*)(hT + b * 64);
#pragma unroll
    for (int c = 0; c < 16; c++){
        float4 wv = aw[c]; float4 hv = hp[c];
        acc = fmaf(hv.x, wv.x, acc); acc = fmaf(hv.y, wv.y, acc);
        acc = fmaf(hv.z, wv.z, acc); acc = fmaf(hv.w, wv.w, acc);
    }
    float s0v = fast_tanh(acc);
    s[b * 32 + j] = s0v;
    __shared__ float ssh[8][33];
    ssh[g][j] = s0v;
    __syncthreads();
    float a = 0.f;
    const float4* wsp = (const float4*)(attn_w + j * 96);
#pragma unroll
    for (int c = 0; c < 8; c++){
        float4 wv = wsp[c];
        a = fmaf(ssh[g][4 * c + 0], wv.x, a);
        a = fmaf(ssh[g][4 * c + 1], wv.y, a);
        a = fmaf(ssh[g][4 * c + 2], wv.z, a);
        a = fmaf(ssh[g][4 * c + 3], wv.w, a);
    }
    sWs[b * 32 + j] = a;
    if (j == 0) dec_in[b] = x[(size_t)b * 4096 + 511 * 8];
}

// ---------------------------------------------------------------------------
// proj kernel (verified). grid 2048 x 256.
// ---------------------------------------------------------------------------
__global__ __launch_bounds__(256) void proj_kernel(
    const __hip_bfloat16* __restrict__ enc_outT, const float* __restrict__ attn_w,
    __hip_bfloat16* __restrict__ proj)
{
    int j = threadIdx.x & 31, g = threadIdx.x >> 5;
    float w[64];
    const float4* aw = (const float4*)(attn_w + j * 96 + 32);
#pragma unroll
    for (int c = 0; c < 16; c++){
        float4 q = aw[c];
        w[4 * c] = q.x; w[4 * c + 1] = q.y; w[4 * c + 2] = q.z; w[4 * c + 3] = q.w;
    }
    size_t base = (size_t)blockIdx.x * 256 + g * 32;
    for (int r = 0; r < 32; ++r){
        size_t pl = base + r;                      // pl = b*512 + t
        const uint4* ev = (const uint4*)(enc_outT + pl * 64);
        float acc = 0.f;
#pragma unroll
        for (int c = 0; c < 8; c++){
            uint4 pk = ev[c];
            acc = fmaf(bflo(pk.x), w[8 * c + 0], acc);
            acc = fmaf(bfhi(pk.x), w[8 * c + 1], acc);
            acc = fmaf(bflo(pk.y), w[8 * c + 2], acc);
            acc = fmaf(bfhi(pk.y), w[8 * c + 3], acc);
            acc = fmaf(bflo(pk.z), w[8 * c + 4], acc);
            acc = fmaf(bfhi(pk.z), w[8 * c + 5], acc);
            acc = fmaf(bflo(pk.w), w[8 * c + 6], acc);
            acc = fmaf(bfhi(pk.w), w[8 * c + 7], acc);
        }
        int t = (int)(pl & 511);
        int bb = (int)(pl >> 9);
        proj[((size_t)t * 1024 + bb) * 32 + j] = __float2bfloat16(acc);
    }
}

// ---------------------------------------------------------------------------
// Fused 24-step decode, persistent kernel v2: grid 512 x 256, 2 blocks/CU
// (launch_bounds(256,2): VGPR<=256, LDS<=80KB -> co-residency guaranteed).
// Per-block persistent caches (loaded once, reused for all 24 steps):
//   - proj[t=bid] row (64KB)        -> 16 uint4 registers/thread (pA)
//   - enc_outT[b0] (64KB)           -> LDS (encl)
//   - enc_outT[b1] (64KB)           -> 16 uint4 registers/thread (eB)
//   - attn_v                        -> LDS (v_sh)
// b-mapping XCD-swizzled (b0=(bid&7)*64+(bid>>3), b1=b0+512) so same-XCD
// blocks read contiguous Ebuf cachelines.
// Per step: Phase A (scores for t=bid, 4 b's/thread from pA; denom[t] plain
// store) -> gbar -> Phase B (k=0: b0 from LDS; k=1: b1 from regs) -> gbar.
// Per-element arithmetic chains verbatim from the verified kernels.
// ---------------------------------------------------------------------------
__global__ __launch_bounds__(256, 2) void dec_persist(
    const __hip_bfloat16* __restrict__ enc_outT, const __hip_bfloat16* __restrict__ proj,
    const float* __restrict__ s_init, float* __restrict__ sWs,
    const float* __restrict__ dec_in_init, float* __restrict__ Ebuf,
    float* __restrict__ denom, unsigned* __restrict__ bar,
    const float* __restrict__ attn_v,
    const float* __restrict__ demb_w, const float* __restrict__ demb_b,
    const float* __restrict__ dwih, const float* __restrict__ dwhh,
    const float* __restrict__ dbih, const float* __restrict__ dbhh,
    const float* __restrict__ attn_w, const float* __restrict__ fc_w,
    const float* __restrict__ fc_b, float* __restrict__ out)
{
    __shared__ uint4 encl[4096];    // enc_outT[b0], 64KB
    __shared__ float w_sh[512];
    __shared__ float ctxp[4][64];
    __shared__ float rnn_sh[80];
    __shared__ float scur2[2][32];
    __shared__ float gsum[64];
    __shared__ float gin[32], ghn[32];
    __shared__ float snew[32];
    __shared__ float wsum[4];
    __shared__ float dins2[2];
    __shared__ float v_sh[32];

    int tid = threadIdx.x;
    int bid = blockIdx.x;
    int wv = tid >> 6, l = tid & 63;

    int tA = bid;                          // phase-A t
    int b0 = (bid & 7) * 64 + (bid >> 3);  // XCD-clustered
    int b1 = b0 + 512;

    // ---- one-time cache loads ----
    uint4 pA[16];
    {
        const uint4* pr = (const uint4*)(proj + (size_t)tA * 1024 * 32);
#pragma unroll
        for (int c = 0; c < 16; c++) pA[c] = pr[tid * 16 + c];
    }
    uint4 eB[16];
    {
        const uint4* ep1 = (const uint4*)(enc_outT + (size_t)b1 * 32768);
#pragma unroll
        for (int i = 0; i < 16; i++) eB[i] = ep1[i * 256 + tid];
    }
    {
        const uint4* ep0 = (const uint4*)(enc_outT + (size_t)b0 * 32768);
#pragma unroll
        for (int i = 0; i < 16; i++) encl[i * 256 + tid] = ep0[i * 256 + tid];
    }
    if (tid < 32){
        v_sh[tid] = attn_v[tid];
        scur2[0][tid] = s_init[b0 * 32 + tid];
        scur2[1][tid] = s_init[b1 * 32 + tid];
    }
    if (tid == 0){
        dins2[0] = dec_in_init[b0];
        dins2[1] = dec_in_init[b1];
    }
    __syncthreads();

    for (int st = 0; st < 24; ++st){
        // ---------------- Phase A: scores for t = tA, b = 4tid..4tid+3 ----
        float Evq[4];
#pragma unroll
        for (int q = 0; q < 4; ++q){
            const float4* sp = (const float4*)(sWs + (4 * tid + q) * 32);
            float acc = 0.f;
#pragma unroll
            for (int c = 0; c < 4; c++){
                uint4 pk = pA[4 * q + c];
                float4 vv0 = *(const float4*)&v_sh[8 * c];
                float4 vv1 = *(const float4*)&v_sh[8 * c + 4];
                float4 s0 = sp[2 * c], s1 = sp[2 * c + 1];
                acc = fmaf(vv0.x, fast_tanh(s0.x + bflo(pk.x)), acc);
                acc = fmaf(vv0.y, fast_tanh(s0.y + bfhi(pk.x)), acc);
                acc = fmaf(vv0.z, fast_tanh(s0.z + bflo(pk.y)), acc);
                acc = fmaf(vv0.w, fast_tanh(s0.w + bfhi(pk.y)), acc);
                acc = fmaf(vv1.x, fast_tanh(s1.x + bflo(pk.z)), acc);
                acc = fmaf(vv1.y, fast_tanh(s1.y + bfhi(pk.z)), acc);
                acc = fmaf(vv1.z, fast_tanh(s1.z + bflo(pk.w)), acc);
                acc = fmaf(vv1.w, fast_tanh(s1.w + bfhi(pk.w)), acc);
            }
            Evq[q] = __builtin_amdgcn_exp2f(LOG2E * acc);
        }
        *(float4*)(Ebuf + (size_t)tA * 1024 + 4 * tid) =
            make_float4(Evq[0], Evq[1], Evq[2], Evq[3]);
        {
            float partial = ((Evq[0] + Evq[1]) + Evq[2]) + Evq[3];
#pragma unroll
            for (int o = 32; o >= 1; o >>= 1) partial += __shfl_xor(partial, o, 64);
            if (l == 0) wsum[wv] = partial;
            __syncthreads();
            if (tid == 0) denom[tA] = wsum[0] + wsum[1] + wsum[2] + wsum[3];
        }

        gbar(bar + 2 * st);

        // ---------------- Phase B, k=0: b0 (enc from LDS) -----------------
        {
            float d0 = denom[tid], d1 = denom[tid + 256];
            float e0 = Ebuf[(size_t)tid * 1024 + b0];
            float e1 = Ebuf[(size_t)(tid + 256) * 1024 + b0];
            w_sh[tid] = e0 * __builtin_amdgcn_rcpf(d0);
            w_sh[tid + 256] = e1 * __builtin_amdgcn_rcpf(d1);
        }
        if (tid < 16) rnn_sh[tid] = fmaxf(fmaf(dins2[0], demb_w[tid], demb_b[tid]), 0.f);
        __syncthreads();
        {
            float acc0 = 0.f, acc1 = 0.f, acc2 = 0.f, acc3 = 0.f;
            float acc4 = 0.f, acc5 = 0.f, acc6 = 0.f, acc7 = 0.f;
#pragma unroll
            for (int i = 0; i < 16; i++){
                int idx = i * 256 + tid;
                uint4 pk = encl[idx];
                float wgt = w_sh[idx >> 3];
                acc0 = fmaf(wgt, bflo(pk.x), acc0);
                acc1 = fmaf(wgt, bfhi(pk.x), acc1);
                acc2 = fmaf(wgt, bflo(pk.y), acc2);
                acc3 = fmaf(wgt, bfhi(pk.y), acc3);
                acc4 = fmaf(wgt, bflo(pk.z), acc4);
                acc5 = fmaf(wgt, bfhi(pk.z), acc5);
                acc6 = fmaf(wgt, bflo(pk.w), acc6);
                acc7 = fmaf(wgt, bfhi(pk.w), acc7);
            }
#pragma unroll
            for (int o = 8; o <= 32; o <<= 1){
                acc0 += __shfl_xor(acc0, o, 64); acc1 += __shfl_xor(acc1, o, 64);
                acc2 += __shfl_xor(acc2, o, 64); acc3 += __shfl_xor(acc3, o, 64);
                acc4 += __shfl_xor(acc4, o, 64); acc5 += __shfl_xor(acc5, o, 64);
                acc6 += __shfl_xor(acc6, o, 64); acc7 += __shfl_xor(acc7, o, 64);
            }
            if (l < 8){
                float* cp = &ctxp[wv][l * 8];
                cp[0] = acc0; cp[1] = acc1; cp[2] = acc2; cp[3] = acc3;
                cp[4] = acc4; cp[5] = acc5; cp[6] = acc6; cp[7] = acc7;
            }
        }
        __syncthreads();
        if (tid < 64) rnn_sh[16 + tid] = ctxp[0][tid] + ctxp[1][tid] + ctxp[2][tid] + ctxp[3][tid];
        __syncthreads();

        if (tid < 96){
            int row = tid;
            float gi = dbih[row];
            const float4* wr = (const float4*)(dwih + row * 80);
#pragma unroll
            for (int c = 0; c < 20; c++){
                float4 wv4 = wr[c];
                gi = fmaf(rnn_sh[4 * c + 0], wv4.x, gi);
                gi = fmaf(rnn_sh[4 * c + 1], wv4.y, gi);
                gi = fmaf(rnn_sh[4 * c + 2], wv4.z, gi);
                gi = fmaf(rnn_sh[4 * c + 3], wv4.w, gi);
            }
            float gh = dbhh[row];
            const float4* urow = (const float4*)(dwhh + row * 32);
#pragma unroll
            for (int c = 0; c < 8; c++){
                float4 wv4 = urow[c];
                gh = fmaf(scur2[0][4 * c + 0], wv4.x, gh);
                gh = fmaf(scur2[0][4 * c + 1], wv4.y, gh);
                gh = fmaf(scur2[0][4 * c + 2], wv4.z, gh);
                gh = fmaf(scur2[0][4 * c + 3], wv4.w, gh);
            }
            if (row < 64) gsum[row] = gi + gh;
            else { gin[row - 64] = gi; ghn[row - 64] = gh; }
        }
        __syncthreads();
        if (tid < 32){
            float r = fast_sigmoid(gsum[tid]);
            float z = fast_sigmoid(gsum[32 + tid]);
            float cand = fast_tanh(fmaf(r, ghn[tid], gin[tid]));
            float sn = (1.f - z) * cand + z * scur2[0][tid];
            snew[tid] = sn;
            scur2[0][tid] = sn;
        }
        __syncthreads();
        if (tid < 32){
            float a = 0.f;
            const float4* aw = (const float4*)(attn_w + tid * 96);
#pragma unroll
            for (int c = 0; c < 8; c++){
                float4 wv4 = aw[c];
                a = fmaf(snew[4 * c + 0], wv4.x, a);
                a = fmaf(snew[4 * c + 1], wv4.y, a);
                a = fmaf(snew[4 * c + 2], wv4.z, a);
                a = fmaf(snew[4 * c + 3], wv4.w, a);
            }
            sWs[b0 * 32 + tid] = a;
        } else if (tid >= 64 && tid < 128){
            int ll = tid - 64;
            float cv0 = (ll < 32) ? snew[ll] : rnn_sh[ll - 16];
            float p = cv0 * fc_w[ll];
            if (ll < 48){
                int i = 64 + ll;
                float cv1 = (i < 96) ? rnn_sh[i - 16] : rnn_sh[i - 96];
                p = fmaf(cv1, fc_w[i], p);
            }
#pragma unroll
            for (int o = 32; o >= 1; o >>= 1) p += __shfl_xor(p, o, 64);
            if (ll == 0){
                float pred = p + fc_b[0];
                out[b0 * 24 + st] = pred;
                dins2[0] = pred;
            }
        }
        __syncthreads();

        // ---------------- Phase B, k=1: b1 (enc from registers) -----------
        {
            float d0 = denom[tid], d1 = denom[tid + 256];
            float e0 = Ebuf[(size_t)tid * 1024 + b1];
            float e1 = Ebuf[(size_t)(tid + 256) * 1024 + b1];
            w_sh[tid] = e0 * __builtin_amdgcn_rcpf(d0);
            w_sh[tid + 256] = e1 * __builtin_amdgcn_rcpf(d1);
        }
        if (tid < 16) rnn_sh[tid] = fmaxf(fmaf(dins2[1], demb_w[tid], demb_b[tid]), 0.f);
        __syncthreads();
        {
            float acc0 = 0.f, acc1 = 0.f, acc2 = 0.f, acc3 = 0.f;
            float acc4 = 0.f, acc5 = 0.f, acc6 = 0.f, acc7 = 0.f;
#pragma unroll
            for (int i = 0; i < 16; i++){
                int idx = i * 256 + tid;
                uint4 pk = eB[i];
                float wgt = w_sh[idx >> 3];
                acc0 = fmaf(wgt, bflo(pk.x), acc0);
                acc1 = fmaf(wgt, bfhi(pk.x), acc1);
                acc2 = fmaf(wgt, bflo(pk.y), acc2);
                acc3 = fmaf(wgt, bfhi(pk.y), acc3);
                acc4 = fmaf(wgt, bflo(pk.z), acc4);
                acc5 = fmaf(wgt, bfhi(pk.z), acc5);
                acc6 = fmaf(wgt, bflo(pk.w), acc6);
                acc7 = fmaf(wgt, bfhi(pk.w), acc7);
            }
#pragma unroll
            for (int o = 8; o <= 32; o <<= 1){
                acc0 += __shfl_xor(acc0, o, 64); acc1 += __shfl_xor(acc1, o, 64);
                acc2 += __shfl_xor(acc2, o, 64); acc3 += __shfl_xor(acc3, o, 64);
                acc4 += __shfl_xor(acc4, o, 64); acc5 += __shfl_xor(acc5, o, 64);
                acc6 += __shfl_xor(acc6, o, 64); acc7 += __shfl_xor(acc7, o, 64);
            }
            if (l < 8){
                float* cp = &ctxp[wv][l * 8];
                cp[0] = acc0; cp[1] = acc1; cp[2] = acc2; cp[3] = acc3;
                cp[4] = acc4; cp[5] = acc5; cp[6] = acc6; cp[7] = acc7;
            }
        }
        __syncthreads();
        if (tid < 64) rnn_sh[16 + tid] = ctxp[0][tid] + ctxp[1][tid] + ctxp[2][tid] + ctxp[3][tid];
        __syncthreads();

        if (tid < 96){
            int row = tid;
            float gi = dbih[row];
            const float4* wr = (const float4*)(dwih + row * 80);
#pragma unroll
            for (int c = 0; c < 20; c++){
                float4 wv4 = wr[c];
                gi = fmaf(rnn_sh[4 * c + 0], wv4.x, gi);
                gi = fmaf(rnn_sh[4 * c + 1], wv4.y, gi);
                gi = fmaf(rnn_sh[4 * c + 2], wv4.z, gi);
                gi = fmaf(rnn_sh[4 * c + 3], wv4.w, gi);
            }
            float gh = dbhh[row];
            const float4* urow = (const float4*)(dwhh + row * 32);
#pragma unroll
            for (int c = 0; c < 8; c++){
                float4 wv4 = urow[c];
                gh = fmaf(scur2[1][4 * c + 0], wv4.x, gh);
                gh = fmaf(scur2[1][4 * c + 1], wv4.y, gh);
                gh = fmaf(scur2[1][4 * c + 2], wv4.z, gh);
                gh = fmaf(scur2[1][4 * c + 3], wv4.w, gh);
            }
            if (row < 64) gsum[row] = gi + gh;
            else { gin[row - 64] = gi; ghn[row - 64] = gh; }
        }
        __syncthreads();
        if (tid < 32){
            float r = fast_sigmoid(gsum[tid]);
            float z = fast_sigmoid(gsum[32 + tid]);
            float cand = fast_tanh(fmaf(r, ghn[tid], gin[tid]));
            float sn = (1.f - z) * cand + z * scur2[1][tid];
            snew[tid] = sn;
            scur2[1][tid] = sn;
        }
        __syncthreads();
        if (tid < 32){
            float a = 0.f;
            const float4* aw = (const float4*)(attn_w + tid * 96);
#pragma unroll
            for (int c = 0; c < 8; c++){
                float4 wv4 = aw[c];
                a = fmaf(snew[4 * c + 0], wv4.x, a);
                a = fmaf(snew[4 * c + 1], wv4.y, a);
                a = fmaf(snew[4 * c + 2], wv4.z, a);
                a = fmaf(snew[4 * c + 3], wv4.w, a);
            }
            sWs[b1 * 32 + tid] = a;
        } else if (tid >= 64 && tid < 128){
            int ll = tid - 64;
            float cv0 = (ll < 32) ? snew[ll] : rnn_sh[ll - 16];
            float p = cv0 * fc_w[ll];
            if (ll < 48){
                int i = 64 + ll;
                float cv1 = (i < 96) ? rnn_sh[i - 16] : rnn_sh[i - 96];
                p = fmaf(cv1, fc_w[i], p);
            }
#pragma unroll
            for (int o = 32; o >= 1; o >>= 1) p += __shfl_xor(p, o, 64);
            if (ll == 0){
                float pred = p + fc_b[0];
                out[b1 * 24 + st] = pred;
                dins2[1] = pred;
            }
        }

        gbar(bar + 2 * st + 1);
    }
}

// ---------------------------------------------------------------------------
extern "C" void kernel_launch(void* const* d_in, const int* in_sizes, int n_in,
                              void* d_out, int out_size, void* d_ws, size_t ws_size,
                              hipStream_t stream)
{
    const float* x      = (const float*)d_in[0];
    const float* emb_w  = (const float*)d_in[2];
    const float* emb_b  = (const float*)d_in[3];
    const float* wih_f  = (const float*)d_in[4];
    const float* whh_f  = (const float*)d_in[5];
    const float* bih_f  = (const float*)d_in[6];
    const float* bhh_f  = (const float*)d_in[7];
    const float* wih_b  = (const float*)d_in[8];
    const float* whh_b  = (const float*)d_in[9];
    const float* bih_b  = (const float*)d_in[10];
    const float* bhh_b  = (const float*)d_in[11];
    const float* act_w  = (const float*)d_in[12];
    const float* act_b  = (const float*)d_in[13];
    const float* attn_w = (const float*)d_in[14];
    const float* attn_v = (const float*)d_in[15];
    const float* demb_w = (const float*)d_in[16];
    const float* demb_b = (const float*)d_in[17];
    const float* dwih   = (const float*)d_in[18];
    const float* dwhh   = (const float*)d_in[19];
    const float* dbih   = (const float*)d_in[20];
    const float* dbhh   = (const float*)d_in[21];
    const float* fc_w   = (const float*)d_in[22];
    const float* fc_b   = (const float*)d_in[23];
    (void)in_sizes; (void)n_in; (void)out_size; (void)ws_size;

    char* w = (char*)d_ws;
    __hip_bfloat16* enc_outT = (__hip_bfloat16*)w;                // [b][t][64] bf16, 67108864 B
    __hip_bfloat16* proj     = (__hip_bfloat16*)(w + 67108864);   // [t][b][32] bf16, 33554432 B
    float* hT     = (float*)(w + 100663296);                      // 1024*64*4
    float* s      = (float*)(w + 100925440);                      // 1024*32*4
    float* sWs    = (float*)(w + 101056512);                      // 1024*32*4
    float* Ebuf   = (float*)(w + 101187584);                      // [t][b] f32, 2097152 B
    float* denom  = (float*)(w + 103284736);                      // 512*4
    unsigned* bar = (unsigned*)(w + 103286784);                   // 48*4 barrier counters
    float* dec_in = (float*)(w + 103333888);                      // 1024*4
    float* out = (float*)d_out;

    enc_kernel<<<512, 256, 0, stream>>>(x, emb_w, emb_b, wih_f, whh_f, bih_f, bhh_f,
                                        wih_b, whh_b, bih_b, bhh_b, enc_outT, hT);
    s0_kernel<<<128, 256, 0, stream>>>(hT, act_w, act_b, attn_w, x, s, sWs, dec_in, bar);
    proj_kernel<<<2048, 256, 0, stream>>>(enc_outT, attn_w, proj);
    dec_persist<<<512, 256, 0, stream>>>(enc_outT, proj, s, sWs, dec_in, Ebuf, denom, bar,
                                         attn_v, demb_w, demb_b, dwih, dwhh, dbih, dbhh,
                                         attn_w, fc_w, fc_b, out);
}

// Round 8
// 1145.511 us; speedup vs baseline: 5.1435x; 4.1618x over previous
//
#include <hip/hip_runtime.h>
#include <hip/hip_bf16.h>
#include <stdint.h>
#include <stddef.h>

// Problem dims: B=1024, T=512, F=8, E=16, H=32, O=1, TO=24

#define LOG2E 1.44269504088896340736f

__device__ __forceinline__ float fast_sigmoid(float x){
    return __builtin_amdgcn_rcpf(1.f + __builtin_amdgcn_exp2f(-LOG2E * x));
}
__device__ __forceinline__ float fast_tanh(float x){
    return 1.f - 2.f * __builtin_amdgcn_rcpf(1.f + __builtin_amdgcn_exp2f(2.f * LOG2E * x));
}
__device__ __forceinline__ float bflo(unsigned u){ return __uint_as_float(u << 16); }
__device__ __forceinline__ float bfhi(unsigned u){ return __uint_as_float(u & 0xffff0000u); }
__device__ __forceinline__ float bperm(int addr, float v){
    return __int_as_float(__builtin_amdgcn_ds_bpermute(addr, __float_as_int(v)));
}

// ---------------------------------------------------------------------------
// Encoder: bidirectional GRU, ONE WAVE per sequence. (R3 verified: 254 µs,
// VALUBusy 84%.) Batched ds_read_b128 broadcasts + ds_bpermute half-combine.
// grid 512 x 256 (4 seqs/block, 2048 waves = 2 waves/SIMD).
// ---------------------------------------------------------------------------
__global__ __launch_bounds__(256, 2) void enc_kernel(
    const float* __restrict__ x,
    const float* __restrict__ emb_w, const float* __restrict__ emb_b,
    const float* __restrict__ wih_f, const float* __restrict__ whh_f,
    const float* __restrict__ bih_f, const float* __restrict__ bhh_f,
    const float* __restrict__ wih_b, const float* __restrict__ whh_b,
    const float* __restrict__ bih_b, const float* __restrict__ bhh_b,
    __hip_bfloat16* __restrict__ enc_outT, float* __restrict__ hT)
{
    __shared__ float lme[4][16];
    __shared__ float lh[4][32];

    int tid = threadIdx.x;
    int l = tid & 63;
    int wv = tid >> 6;
    int j = l & 31;
    int p = l >> 5;
    int S = blockIdx.x * 4 + wv;        // 0..2047
    int dir = S >> 10;
    int b = S & 1023;
    const float* wih = dir ? wih_b : wih_f;
    const float* whh = dir ? whh_b : whh_f;
    const float* bih = dir ? bih_b : bih_f;
    const float* bhh = dir ? bhh_b : bhh_f;

    float wr[8], wz[8], wn[8];
#pragma unroll
    for (int e = 0; e < 8; e++){
        int ee = 8 * p + e;
        wr[e] = wih[j * 16 + ee];
        wz[e] = wih[(32 + j) * 16 + ee];
        wn[e] = wih[(64 + j) * 16 + ee];
    }
    float ur[16], uz[16], un[16];
#pragma unroll
    for (int k = 0; k < 16; k++){
        int kk = 16 * p + k;
        ur[k] = whh[j * 32 + kk];
        uz[k] = whh[(32 + j) * 32 + kk];
        un[k] = whh[(64 + j) * 32 + kk];
    }
    float c_r  = p ? 0.f : (bih[j] + bhh[j]);
    float c_z  = p ? 0.f : (bih[32 + j] + bhh[32 + j]);
    float c_ni = p ? 0.f : bih[64 + j];
    float c_nh = p ? 0.f : bhh[64 + j];

    float ew[8];
#pragma unroll
    for (int f = 0; f < 8; f++) ew[f] = emb_w[(l & 15) * 8 + f];
    float ebias = emb_b[l & 15];

    int aX = 4 * (l ^ 32);

    float h = 0.f;
    const float* xp = x + (size_t)b * 4096 + (dir ? 511 * 8 : 0);
    __hip_bfloat16* op = enc_outT + ((size_t)b * 512 + (dir ? 511 : 0)) * 64 + dir * 32 + j;
    int xstep = dir ? -8 : 8;
    ptrdiff_t ostep = dir ? -64 : 64;

    float4 cx0 = ((const float4*)xp)[0];
    float4 cx1 = ((const float4*)xp)[1];

    float me;
    {
        float e0 = ebias;
        e0 = fmaf(cx0.x, ew[0], e0); e0 = fmaf(cx0.y, ew[1], e0);
        e0 = fmaf(cx0.z, ew[2], e0); e0 = fmaf(cx0.w, ew[3], e0);
        e0 = fmaf(cx1.x, ew[4], e0); e0 = fmaf(cx1.y, ew[5], e0);
        e0 = fmaf(cx1.z, ew[6], e0); e0 = fmaf(cx1.w, ew[7], e0);
        me = fmaxf(e0, 0.f);
    }
    if (l < 16) lme[wv][l] = me;
    if (l < 32) lh[wv][l] = h;

    const float4* pe = (const float4*)(&lme[wv][8 * p]);
    const float4* ph = (const float4*)(&lh[wv][16 * p]);

    for (int it = 0; it < 512; ++it){
        const float* np = (it == 511) ? xp : (xp + xstep);
        float4 nx0 = ((const float4*)np)[0];
        float4 nx1 = ((const float4*)np)[1];

        float4 e01 = pe[0], e23 = pe[1];
        float4 h0 = ph[0], h1 = ph[1], h2 = ph[2], h3 = ph[3];

        float Ar = c_r, Az = c_z, Ani = c_ni, Anh = c_nh;

        Ar = fmaf(e01.x, wr[0], Ar); Az = fmaf(e01.x, wz[0], Az); Ani = fmaf(e01.x, wn[0], Ani);
        Ar = fmaf(e01.y, wr[1], Ar); Az = fmaf(e01.y, wz[1], Az); Ani = fmaf(e01.y, wn[1], Ani);
        Ar = fmaf(e01.z, wr[2], Ar); Az = fmaf(e01.z, wz[2], Az); Ani = fmaf(e01.z, wn[2], Ani);
        Ar = fmaf(e01.w, wr[3], Ar); Az = fmaf(e01.w, wz[3], Az); Ani = fmaf(e01.w, wn[3], Ani);
        Ar = fmaf(e23.x, wr[4], Ar); Az = fmaf(e23.x, wz[4], Az); Ani = fmaf(e23.x, wn[4], Ani);
        Ar = fmaf(e23.y, wr[5], Ar); Az = fmaf(e23.y, wz[5], Az); Ani = fmaf(e23.y, wn[5], Ani);
        Ar = fmaf(e23.z, wr[6], Ar); Az = fmaf(e23.z, wz[6], Az); Ani = fmaf(e23.z, wn[6], Ani);
        Ar = fmaf(e23.w, wr[7], Ar); Az = fmaf(e23.w, wz[7], Az); Ani = fmaf(e23.w, wn[7], Ani);

        Ar = fmaf(h0.x, ur[0], Ar);  Az = fmaf(h0.x, uz[0], Az);  Anh = fmaf(h0.x, un[0], Anh);
        Ar = fmaf(h0.y, ur[1], Ar);  Az = fmaf(h0.y, uz[1], Az);  Anh = fmaf(h0.y, un[1], Anh);
        Ar = fmaf(h0.z, ur[2], Ar);  Az = fmaf(h0.z, uz[2], Az);  Anh = fmaf(h0.z, un[2], Anh);
        Ar = fmaf(h0.w, ur[3], Ar);  Az = fmaf(h0.w, uz[3], Az);  Anh = fmaf(h0.w, un[3], Anh);
        Ar = fmaf(h1.x, ur[4], Ar);  Az = fmaf(h1.x, uz[4], Az);  Anh = fmaf(h1.x, un[4], Anh);
        Ar = fmaf(h1.y, ur[5], Ar);  Az = fmaf(h1.y, uz[5], Az);  Anh = fmaf(h1.y, un[5], Anh);
        Ar = fmaf(h1.z, ur[6], Ar);  Az = fmaf(h1.z, uz[6], Az);  Anh = fmaf(h1.z, un[6], Anh);
        Ar = fmaf(h1.w, ur[7], Ar);  Az = fmaf(h1.w, uz[7], Az);  Anh = fmaf(h1.w, un[7], Anh);
        Ar = fmaf(h2.x, ur[8], Ar);  Az = fmaf(h2.x, uz[8], Az);  Anh = fmaf(h2.x, un[8], Anh);
        Ar = fmaf(h2.y, ur[9], Ar);  Az = fmaf(h2.y, uz[9], Az);  Anh = fmaf(h2.y, un[9], Anh);
        Ar = fmaf(h2.z, ur[10], Ar); Az = fmaf(h2.z, uz[10], Az); Anh = fmaf(h2.z, un[10], Anh);
        Ar = fmaf(h2.w, ur[11], Ar); Az = fmaf(h2.w, uz[11], Az); Anh = fmaf(h2.w, un[11], Anh);
        Ar = fmaf(h3.x, ur[12], Ar); Az = fmaf(h3.x, uz[12], Az); Anh = fmaf(h3.x, un[12], Anh);
        Ar = fmaf(h3.y, ur[13], Ar); Az = fmaf(h3.y, uz[13], Az); Anh = fmaf(h3.y, un[13], Anh);
        Ar = fmaf(h3.z, ur[14], Ar); Az = fmaf(h3.z, uz[14], Az); Anh = fmaf(h3.z, un[14], Anh);
        Ar = fmaf(h3.w, ur[15], Ar); Az = fmaf(h3.w, uz[15], Az); Anh = fmaf(h3.w, un[15], Anh);

        float tr  = bperm(aX, Ar);
        float tz  = bperm(aX, Az);
        float tni = bperm(aX, Ani);
        float tnh = bperm(aX, Anh);
        Ar  += tr;
        Az  += tz;
        Ani += tni;
        Anh += tnh;

        float r = fast_sigmoid(Ar);
        float z = fast_sigmoid(Az);
        float cand = fast_tanh(fmaf(r, Anh, Ani));
        h = (1.f - z) * cand + z * h;

        if (l < 32) lh[wv][l] = h;
        *op = __float2bfloat16(h);

        float e0 = ebias;
        e0 = fmaf(nx0.x, ew[0], e0); e0 = fmaf(nx0.y, ew[1], e0);
        e0 = fmaf(nx0.z, ew[2], e0); e0 = fmaf(nx0.w, ew[3], e0);
        e0 = fmaf(nx1.x, ew[4], e0); e0 = fmaf(nx1.y, ew[5], e0);
        e0 = fmaf(nx1.z, ew[6], e0); e0 = fmaf(nx1.w, ew[7], e0);
        me = fmaxf(e0, 0.f);
        if (l < 16) lme[wv][l] = me;

        xp = np; op += ostep;
    }
    hT[b * 64 + dir * 32 + j] = h;
}

// ---------------------------------------------------------------------------
// s0 = tanh([hTf,hTb] @ act_w^T + act_b); sWs0 = s0 @ Ws^T; dec_in0 = x[:,511,0].
// Also zeroes the 24*512 softmax denominators (block 0). grid 128 x 256.
// ---------------------------------------------------------------------------
__global__ __launch_bounds__(256) void s0_kernel(
    const float* __restrict__ hT, const float* __restrict__ act_w, const float* __restrict__ act_b,
    const float* __restrict__ attn_w, const float* __restrict__ x,
    float* __restrict__ s, float* __restrict__ sWs, float* __restrict__ dec_in,
    float* __restrict__ denom)
{
    if (blockIdx.x == 0){
        for (int i = threadIdx.x; i < 24 * 512; i += 256) denom[i] = 0.f;
    }
    int j = threadIdx.x & 31, g = threadIdx.x >> 5;
    int b = blockIdx.x * 8 + g;
    float acc = act_b[j];
    const float4* aw = (const float4*)(act_w + j * 64);
    const float4* hp = (const float4*)(hT + b * 64);
#pragma unroll
    for (int c = 0; c < 16; c++){
        float4 wv = aw[c]; float4 hv = hp[c];
        acc = fmaf(hv.x, wv.x, acc); acc = fmaf(hv.y, wv.y, acc);
        acc = fmaf(hv.z, wv.z, acc); acc = fmaf(hv.w, wv.w, acc);
    }
    float s0v = fast_tanh(acc);
    s[b * 32 + j] = s0v;
    __shared__ float ssh[8][33];
    ssh[g][j] = s0v;
    __syncthreads();
    float a = 0.f;
    const float4* wsp = (const float4*)(attn_w + j * 96);   // Ws = attn_w[:, :32]
#pragma unroll
    for (int c = 0; c < 8; c++){
        float4 wv = wsp[c];
        a = fmaf(ssh[g][4 * c + 0], wv.x, a);
        a = fmaf(ssh[g][4 * c + 1], wv.y, a);
        a = fmaf(ssh[g][4 * c + 2], wv.z, a);
        a = fmaf(ssh[g][4 * c + 3], wv.w, a);
    }
    sWs[b * 32 + j] = a;
    if (j == 0) dec_in[b] = x[(size_t)b * 4096 + 511 * 8];
}

// ---------------------------------------------------------------------------
// enc_proj[t,b,j] = sum_d enc_outT[b,t,d] * We[j,d];  We = attn_w[:, 32:96]
// Reads enc_outT rows ([b][t][64] contiguous), writes proj in [t][b][32].
// grid 2048 x 256.
// ---------------------------------------------------------------------------
__global__ __launch_bounds__(256) void proj_kernel(
    const __hip_bfloat16* __restrict__ enc_outT, const float* __restrict__ attn_w,
    __hip_bfloat16* __restrict__ proj)
{
    int j = threadIdx.x & 31, g = threadIdx.x >> 5;
    float w[64];
    const float4* aw = (const float4*)(attn_w + j * 96 + 32);
#pragma unroll
    for (int c = 0; c < 16; c++){
        float4 q = aw[c];
        w[4 * c] = q.x; w[4 * c + 1] = q.y; w[4 * c + 2] = q.z; w[4 * c + 3] = q.w;
    }
    size_t base = (size_t)blockIdx.x * 256 + g * 32;
    for (int r = 0; r < 32; ++r){
        size_t pl = base + r;                      // pl = b*512 + t
        const uint4* ev = (const uint4*)(enc_outT + pl * 64);
        float acc = 0.f;
#pragma unroll
        for (int c = 0; c < 8; c++){
            uint4 pk = ev[c];
            acc = fmaf(bflo(pk.x), w[8 * c + 0], acc);
            acc = fmaf(bfhi(pk.x), w[8 * c + 1], acc);
            acc = fmaf(bflo(pk.y), w[8 * c + 2], acc);
            acc = fmaf(bfhi(pk.y), w[8 * c + 3], acc);
            acc = fmaf(bflo(pk.z), w[8 * c + 4], acc);
            acc = fmaf(bfhi(pk.z), w[8 * c + 5], acc);
            acc = fmaf(bflo(pk.w), w[8 * c + 6], acc);
            acc = fmaf(bfhi(pk.w), w[8 * c + 7], acc);
        }
        int t = (int)(pl & 511);
        int bb = (int)(pl >> 9);
        proj[((size_t)t * 1024 + bb) * 32 + j] = __float2bfloat16(acc);
    }
}

// ---------------------------------------------------------------------------
// Attention scores v2: each block handles TWO consecutive t's sharing one
// sWs read (halves the 64 MB/step sWs re-read and the block count).
// Per-t math, shuffle tree, and per-(t,chunk) atomicAdd grouping are
// bit-identical to the verified R3 kernel. grid 1024 (= 256 t-pairs * 4
// b-chunks) x 256.
// ---------------------------------------------------------------------------
__global__ __launch_bounds__(256) void attn_kernel(
    const __hip_bfloat16* __restrict__ proj, const float* __restrict__ sWs,
    const float* __restrict__ attn_v, float* __restrict__ Ebuf, float* __restrict__ denom)
{
    int t0 = (blockIdx.x >> 2) * 2;
    int t1 = t0 + 1;
    int b = (blockIdx.x & 3) * 256 + threadIdx.x;
    float v[32];
    {
        const float4* vv = (const float4*)attn_v;
#pragma unroll
        for (int c = 0; c < 8; c++){
            float4 q = vv[c];
            v[4 * c] = q.x; v[4 * c + 1] = q.y; v[4 * c + 2] = q.z; v[4 * c + 3] = q.w;
        }
    }
    // sWs[b] loaded once, shared by both t's
    float sv[32];
    {
        const float4* sp = (const float4*)(sWs + b * 32);
#pragma unroll
        for (int c = 0; c < 8; c++){
            float4 q = sp[c];
            sv[4 * c] = q.x; sv[4 * c + 1] = q.y; sv[4 * c + 2] = q.z; sv[4 * c + 3] = q.w;
        }
    }
    const uint4* pp0 = (const uint4*)(proj + ((size_t)t0 * 1024 + b) * 32);
    const uint4* pp1 = (const uint4*)(proj + ((size_t)t1 * 1024 + b) * 32);
    float acc0 = 0.f, acc1 = 0.f;
#pragma unroll
    for (int c = 0; c < 4; c++){
        uint4 pk0 = pp0[c];
        uint4 pk1 = pp1[c];
        acc0 = fmaf(v[8 * c + 0], fast_tanh(sv[8 * c + 0] + bflo(pk0.x)), acc0);
        acc0 = fmaf(v[8 * c + 1], fast_tanh(sv[8 * c + 1] + bfhi(pk0.x)), acc0);
        acc0 = fmaf(v[8 * c + 2], fast_tanh(sv[8 * c + 2] + bflo(pk0.y)), acc0);
        acc0 = fmaf(v[8 * c + 3], fast_tanh(sv[8 * c + 3] + bfhi(pk0.y)), acc0);
        acc0 = fmaf(v[8 * c + 4], fast_tanh(sv[8 * c + 4] + bflo(pk0.z)), acc0);
        acc0 = fmaf(v[8 * c + 5], fast_tanh(sv[8 * c + 5] + bfhi(pk0.z)), acc0);
        acc0 = fmaf(v[8 * c + 6], fast_tanh(sv[8 * c + 6] + bflo(pk0.w)), acc0);
        acc0 = fmaf(v[8 * c + 7], fast_tanh(sv[8 * c + 7] + bfhi(pk0.w)), acc0);
        acc1 = fmaf(v[8 * c + 0], fast_tanh(sv[8 * c + 0] + bflo(pk1.x)), acc1);
        acc1 = fmaf(v[8 * c + 1], fast_tanh(sv[8 * c + 1] + bfhi(pk1.x)), acc1);
        acc1 = fmaf(v[8 * c + 2], fast_tanh(sv[8 * c + 2] + bflo(pk1.y)), acc1);
        acc1 = fmaf(v[8 * c + 3], fast_tanh(sv[8 * c + 3] + bfhi(pk1.y)), acc1);
        acc1 = fmaf(v[8 * c + 4], fast_tanh(sv[8 * c + 4] + bflo(pk1.z)), acc1);
        acc1 = fmaf(v[8 * c + 5], fast_tanh(sv[8 * c + 5] + bfhi(pk1.z)), acc1);
        acc1 = fmaf(v[8 * c + 6], fast_tanh(sv[8 * c + 6] + bflo(pk1.w)), acc1);
        acc1 = fmaf(v[8 * c + 7], fast_tanh(sv[8 * c + 7] + bfhi(pk1.w)), acc1);
    }
    float Ev0 = __builtin_amdgcn_exp2f(LOG2E * acc0);
    float Ev1 = __builtin_amdgcn_exp2f(LOG2E * acc1);
    Ebuf[(size_t)t0 * 1024 + b] = Ev0;
    Ebuf[(size_t)t1 * 1024 + b] = Ev1;
    float r0 = Ev0, r1 = Ev1;
#pragma unroll
    for (int o = 32; o >= 1; o >>= 1){
        r0 += __shfl_xor(r0, o, 64);
        r1 += __shfl_xor(r1, o, 64);
    }
    __shared__ float wsum0[4], wsum1[4];
    if ((threadIdx.x & 63) == 0){
        wsum0[threadIdx.x >> 6] = r0;
        wsum1[threadIdx.x >> 6] = r1;
    }
    __syncthreads();
    if (threadIdx.x == 0){
        atomicAdd(denom + t0, wsum0[0] + wsum0[1] + wsum0[2] + wsum0[3]);
        atomicAdd(denom + t1, wsum1[0] + wsum1[1] + wsum1[2] + wsum1[3]);
    }
}

// ---------------------------------------------------------------------------
// Decoder step (R3 verified): block b. E-column + denom -> LDS weights;
// ctx from enc_outT[b] = contiguous 64KB coalesced uint4 loads; shuffle-
// reduce; GRU cell + fc + next sWs. grid 1024 x 256.
// ---------------------------------------------------------------------------
__global__ __launch_bounds__(256) void dec_kernel(
    const __hip_bfloat16* __restrict__ enc_outT, const float* __restrict__ Ebuf,
    const float* __restrict__ denom, float* __restrict__ s, float* __restrict__ sWs,
    float* __restrict__ dec_in,
    const float* __restrict__ demb_w, const float* __restrict__ demb_b,
    const float* __restrict__ dwih, const float* __restrict__ dwhh,
    const float* __restrict__ dbih, const float* __restrict__ dbhh,
    const float* __restrict__ attn_w, const float* __restrict__ fc_w,
    const float* __restrict__ fc_b, float* __restrict__ out, int step)
{
    __shared__ float w_sh[512];
    __shared__ float ctxp[4][64];
    __shared__ float rnn_sh[80];    // [embd(16), ctx(64)]
    __shared__ float scur[32];
    __shared__ float gsum[64];
    __shared__ float gin[32], ghn[32];
    __shared__ float snew[32];
    int tid = threadIdx.x;
    int b = blockIdx.x;
    int wv = tid >> 6, l = tid & 63;

    float d0 = denom[tid], d1 = denom[tid + 256];
    float e0 = Ebuf[(size_t)tid * 1024 + b];
    float e1 = Ebuf[(size_t)(tid + 256) * 1024 + b];
    w_sh[tid] = e0 * __builtin_amdgcn_rcpf(d0);
    w_sh[tid + 256] = e1 * __builtin_amdgcn_rcpf(d1);
    if (tid < 16) rnn_sh[tid] = fmaxf(fmaf(dec_in[b], demb_w[tid], demb_b[tid]), 0.f);
    if (tid >= 32 && tid < 64) scur[tid - 32] = s[b * 32 + tid - 32];
    __syncthreads();

    float acc0 = 0.f, acc1 = 0.f, acc2 = 0.f, acc3 = 0.f;
    float acc4 = 0.f, acc5 = 0.f, acc6 = 0.f, acc7 = 0.f;
    const uint4* ep = (const uint4*)(enc_outT + (size_t)b * 32768);
#pragma unroll
    for (int i = 0; i < 16; i++){
        int idx = i * 256 + tid;
        uint4 pk = ep[idx];
        float wgt = w_sh[idx >> 3];
        acc0 = fmaf(wgt, bflo(pk.x), acc0);
        acc1 = fmaf(wgt, bfhi(pk.x), acc1);
        acc2 = fmaf(wgt, bflo(pk.y), acc2);
        acc3 = fmaf(wgt, bfhi(pk.y), acc3);
        acc4 = fmaf(wgt, bflo(pk.z), acc4);
        acc5 = fmaf(wgt, bfhi(pk.z), acc5);
        acc6 = fmaf(wgt, bflo(pk.w), acc6);
        acc7 = fmaf(wgt, bfhi(pk.w), acc7);
    }
#pragma unroll
    for (int o = 8; o <= 32; o <<= 1){
        acc0 += __shfl_xor(acc0, o, 64); acc1 += __shfl_xor(acc1, o, 64);
        acc2 += __shfl_xor(acc2, o, 64); acc3 += __shfl_xor(acc3, o, 64);
        acc4 += __shfl_xor(acc4, o, 64); acc5 += __shfl_xor(acc5, o, 64);
        acc6 += __shfl_xor(acc6, o, 64); acc7 += __shfl_xor(acc7, o, 64);
    }
    if (l < 8){
        float* cp = &ctxp[wv][l * 8];
        cp[0] = acc0; cp[1] = acc1; cp[2] = acc2; cp[3] = acc3;
        cp[4] = acc4; cp[5] = acc5; cp[6] = acc6; cp[7] = acc7;
    }
    __syncthreads();
    if (tid < 64) rnn_sh[16 + tid] = ctxp[0][tid] + ctxp[1][tid] + ctxp[2][tid] + ctxp[3][tid];
    __syncthreads();

    if (tid < 96){
        int row = tid;
        float gi = dbih[row];
        const float4* wr = (const float4*)(dwih + row * 80);
#pragma unroll
        for (int c = 0; c < 20; c++){
            float4 wv4 = wr[c];
            gi = fmaf(rnn_sh[4 * c + 0], wv4.x, gi);
            gi = fmaf(rnn_sh[4 * c + 1], wv4.y, gi);
            gi = fmaf(rnn_sh[4 * c + 2], wv4.z, gi);
            gi = fmaf(rnn_sh[4 * c + 3], wv4.w, gi);
        }
        float gh = dbhh[row];
        const float4* urow = (const float4*)(dwhh + row * 32);
#pragma unroll
        for (int c = 0; c < 8; c++){
            float4 wv4 = urow[c];
            gh = fmaf(scur[4 * c + 0], wv4.x, gh);
            gh = fmaf(scur[4 * c + 1], wv4.y, gh);
            gh = fmaf(scur[4 * c + 2], wv4.z, gh);
            gh = fmaf(scur[4 * c + 3], wv4.w, gh);
        }
        if (row < 64) gsum[row] = gi + gh;
        else { gin[row - 64] = gi; ghn[row - 64] = gh; }
    }
    __syncthreads();

    if (tid < 32){
        float r = fast_sigmoid(gsum[tid]);
        float z = fast_sigmoid(gsum[32 + tid]);
        float cand = fast_tanh(fmaf(r, ghn[tid], gin[tid]));
        float sn = (1.f - z) * cand + z * scur[tid];
        snew[tid] = sn;
        s[b * 32 + tid] = sn;
    }
    __syncthreads();

    if (tid < 32){   // next-step sWs
        float a = 0.f;
        const float4* aw = (const float4*)(attn_w + tid * 96);
#pragma unroll
        for (int c = 0; c < 8; c++){
            float4 wv4 = aw[c];
            a = fmaf(snew[4 * c + 0], wv4.x, a);
            a = fmaf(snew[4 * c + 1], wv4.y, a);
            a = fmaf(snew[4 * c + 2], wv4.z, a);
            a = fmaf(snew[4 * c + 3], wv4.w, a);
        }
        sWs[b * 32 + tid] = a;
    } else if (tid >= 64 && tid < 128){   // fc: pred = cat(112) . fc_w + fc_b
        int ll = tid - 64;
        float cv0 = (ll < 32) ? snew[ll] : rnn_sh[ll - 16];
        float p = cv0 * fc_w[ll];
        if (ll < 48){
            int i = 64 + ll;
            float cv1 = (i < 96) ? rnn_sh[i - 16] : rnn_sh[i - 96];
            p = fmaf(cv1, fc_w[i], p);
        }
#pragma unroll
        for (int o = 32; o >= 1; o >>= 1) p += __shfl_xor(p, o, 64);
        if (ll == 0){
            float pred = p + fc_b[0];
            out[b * 24 + step] = pred;
            dec_in[b] = pred;
        }
    }
}

// ---------------------------------------------------------------------------
extern "C" void kernel_launch(void* const* d_in, const int* in_sizes, int n_in,
                              void* d_out, int out_size, void* d_ws, size_t ws_size,
                              hipStream_t stream)
{
    const float* x      = (const float*)d_in[0];
    const float* emb_w  = (const float*)d_in[2];
    const float* emb_b  = (const float*)d_in[3];
    const float* wih_f  = (const float*)d_in[4];
    const float* whh_f  = (const float*)d_in[5];
    const float* bih_f  = (const float*)d_in[6];
    const float* bhh_f  = (const float*)d_in[7];
    const float* wih_b  = (const float*)d_in[8];
    const float* whh_b  = (const float*)d_in[9];
    const float* bih_b  = (const float*)d_in[10];
    const float* bhh_b  = (const float*)d_in[11];
    const float* act_w  = (const float*)d_in[12];
    const float* act_b  = (const float*)d_in[13];
    const float* attn_w = (const float*)d_in[14];
    const float* attn_v = (const float*)d_in[15];
    const float* demb_w = (const float*)d_in[16];
    const float* demb_b = (const float*)d_in[17];
    const float* dwih   = (const float*)d_in[18];
    const float* dwhh   = (const float*)d_in[19];
    const float* dbih   = (const float*)d_in[20];
    const float* dbhh   = (const float*)d_in[21];
    const float* fc_w   = (const float*)d_in[22];
    const float* fc_b   = (const float*)d_in[23];
    (void)in_sizes; (void)n_in; (void)out_size; (void)ws_size;

    char* w = (char*)d_ws;
    __hip_bfloat16* enc_outT = (__hip_bfloat16*)w;                // [b][t][64] bf16, 67108864 B
    __hip_bfloat16* proj     = (__hip_bfloat16*)(w + 67108864);   // [t][b][32] bf16, 33554432 B
    float* hT     = (float*)(w + 100663296);                      // 1024*64*4
    float* s      = (float*)(w + 100925440);                      // 1024*32*4
    float* sWs    = (float*)(w + 101056512);                      // 1024*32*4
    float* Ebuf   = (float*)(w + 101187584);                      // [t][b] f32, 2097152 B
    float* denom  = (float*)(w + 103284736);                      // 24*512*4
    float* dec_in = (float*)(w + 103333888);                      // 1024*4
    float* out = (float*)d_out;

    enc_kernel<<<512, 256, 0, stream>>>(x, emb_w, emb_b, wih_f, whh_f, bih_f, bhh_f,
                                        wih_b, whh_b, bih_b, bhh_b, enc_outT, hT);
    s0_kernel<<<128, 256, 0, stream>>>(hT, act_w, act_b, attn_w, x, s, sWs, dec_in, denom);
    proj_kernel<<<2048, 256, 0, stream>>>(enc_outT, attn_w, proj);
    for (int st = 0; st < 24; ++st){
        attn_kernel<<<1024, 256, 0, stream>>>(proj, sWs, attn_v, Ebuf, denom + st * 512);
        dec_kernel<<<1024, 256, 0, stream>>>(enc_outT, Ebuf, denom + st * 512, s, sWs, dec_in,
                                             demb_w, demb_b, dwih, dwhh, dbih, dbhh,
                                             attn_w, fc_w, fc_b, out, st);
    }
}

// Round 9
// 1106.366 us; speedup vs baseline: 5.3255x; 1.0354x over previous
//
#include <hip/hip_runtime.h>
#include <hip/hip_bf16.h>
#include <stdint.h>
#include <stddef.h>

// Problem dims: B=1024, T=512, F=8, E=16, H=32, O=1, TO=24

#define LOG2E 1.44269504088896340736f

__device__ __forceinline__ float fast_sigmoid(float x){
    return __builtin_amdgcn_rcpf(1.f + __builtin_amdgcn_exp2f(-LOG2E * x));
}
__device__ __forceinline__ float fast_tanh(float x){
    return 1.f - 2.f * __builtin_amdgcn_rcpf(1.f + __builtin_amdgcn_exp2f(2.f * LOG2E * x));
}
__device__ __forceinline__ float bflo(unsigned u){ return __uint_as_float(u << 16); }
__device__ __forceinline__ float bfhi(unsigned u){ return __uint_as_float(u & 0xffff0000u); }
__device__ __forceinline__ float bperm(int addr, float v){
    return __int_as_float(__builtin_amdgcn_ds_bpermute(addr, __float_as_int(v)));
}

// ---------------------------------------------------------------------------
// Encoder: bidirectional GRU, ONE WAVE per sequence. (R3 verified: 254 µs,
// VALUBusy 84%.) Batched ds_read_b128 broadcasts + ds_bpermute half-combine.
// grid 512 x 256 (4 seqs/block, 2048 waves = 2 waves/SIMD). UNCHANGED.
// ---------------------------------------------------------------------------
__global__ __launch_bounds__(256, 2) void enc_kernel(
    const float* __restrict__ x,
    const float* __restrict__ emb_w, const float* __restrict__ emb_b,
    const float* __restrict__ wih_f, const float* __restrict__ whh_f,
    const float* __restrict__ bih_f, const float* __restrict__ bhh_f,
    const float* __restrict__ wih_b, const float* __restrict__ whh_b,
    const float* __restrict__ bih_b, const float* __restrict__ bhh_b,
    __hip_bfloat16* __restrict__ enc_outT, float* __restrict__ hT)
{
    __shared__ float lme[4][16];
    __shared__ float lh[4][32];

    int tid = threadIdx.x;
    int l = tid & 63;
    int wv = tid >> 6;
    int j = l & 31;
    int p = l >> 5;
    int S = blockIdx.x * 4 + wv;        // 0..2047
    int dir = S >> 10;
    int b = S & 1023;
    const float* wih = dir ? wih_b : wih_f;
    const float* whh = dir ? whh_b : whh_f;
    const float* bih = dir ? bih_b : bih_f;
    const float* bhh = dir ? bhh_b : bhh_f;

    float wr[8], wz[8], wn[8];
#pragma unroll
    for (int e = 0; e < 8; e++){
        int ee = 8 * p + e;
        wr[e] = wih[j * 16 + ee];
        wz[e] = wih[(32 + j) * 16 + ee];
        wn[e] = wih[(64 + j) * 16 + ee];
    }
    float ur[16], uz[16], un[16];
#pragma unroll
    for (int k = 0; k < 16; k++){
        int kk = 16 * p + k;
        ur[k] = whh[j * 32 + kk];
        uz[k] = whh[(32 + j) * 32 + kk];
        un[k] = whh[(64 + j) * 32 + kk];
    }
    float c_r  = p ? 0.f : (bih[j] + bhh[j]);
    float c_z  = p ? 0.f : (bih[32 + j] + bhh[32 + j]);
    float c_ni = p ? 0.f : bih[64 + j];
    float c_nh = p ? 0.f : bhh[64 + j];

    float ew[8];
#pragma unroll
    for (int f = 0; f < 8; f++) ew[f] = emb_w[(l & 15) * 8 + f];
    float ebias = emb_b[l & 15];

    int aX = 4 * (l ^ 32);

    float h = 0.f;
    const float* xp = x + (size_t)b * 4096 + (dir ? 511 * 8 : 0);
    __hip_bfloat16* op = enc_outT + ((size_t)b * 512 + (dir ? 511 : 0)) * 64 + dir * 32 + j;
    int xstep = dir ? -8 : 8;
    ptrdiff_t ostep = dir ? -64 : 64;

    float4 cx0 = ((const float4*)xp)[0];
    float4 cx1 = ((const float4*)xp)[1];

    float me;
    {
        float e0 = ebias;
        e0 = fmaf(cx0.x, ew[0], e0); e0 = fmaf(cx0.y, ew[1], e0);
        e0 = fmaf(cx0.z, ew[2], e0); e0 = fmaf(cx0.w, ew[3], e0);
        e0 = fmaf(cx1.x, ew[4], e0); e0 = fmaf(cx1.y, ew[5], e0);
        e0 = fmaf(cx1.z, ew[6], e0); e0 = fmaf(cx1.w, ew[7], e0);
        me = fmaxf(e0, 0.f);
    }
    if (l < 16) lme[wv][l] = me;
    if (l < 32) lh[wv][l] = h;

    const float4* pe = (const float4*)(&lme[wv][8 * p]);
    const float4* ph = (const float4*)(&lh[wv][16 * p]);

    for (int it = 0; it < 512; ++it){
        const float* np = (it == 511) ? xp : (xp + xstep);
        float4 nx0 = ((const float4*)np)[0];
        float4 nx1 = ((const float4*)np)[1];

        float4 e01 = pe[0], e23 = pe[1];
        float4 h0 = ph[0], h1 = ph[1], h2 = ph[2], h3 = ph[3];

        float Ar = c_r, Az = c_z, Ani = c_ni, Anh = c_nh;

        Ar = fmaf(e01.x, wr[0], Ar); Az = fmaf(e01.x, wz[0], Az); Ani = fmaf(e01.x, wn[0], Ani);
        Ar = fmaf(e01.y, wr[1], Ar); Az = fmaf(e01.y, wz[1], Az); Ani = fmaf(e01.y, wn[1], Ani);
        Ar = fmaf(e01.z, wr[2], Ar); Az = fmaf(e01.z, wz[2], Az); Ani = fmaf(e01.z, wn[2], Ani);
        Ar = fmaf(e01.w, wr[3], Ar); Az = fmaf(e01.w, wz[3], Az); Ani = fmaf(e01.w, wn[3], Ani);
        Ar = fmaf(e23.x, wr[4], Ar); Az = fmaf(e23.x, wz[4], Az); Ani = fmaf(e23.x, wn[4], Ani);
        Ar = fmaf(e23.y, wr[5], Ar); Az = fmaf(e23.y, wz[5], Az); Ani = fmaf(e23.y, wn[5], Ani);
        Ar = fmaf(e23.z, wr[6], Ar); Az = fmaf(e23.z, wz[6], Az); Ani = fmaf(e23.z, wn[6], Ani);
        Ar = fmaf(e23.w, wr[7], Ar); Az = fmaf(e23.w, wz[7], Az); Ani = fmaf(e23.w, wn[7], Ani);

        Ar = fmaf(h0.x, ur[0], Ar);  Az = fmaf(h0.x, uz[0], Az);  Anh = fmaf(h0.x, un[0], Anh);
        Ar = fmaf(h0.y, ur[1], Ar);  Az = fmaf(h0.y, uz[1], Az);  Anh = fmaf(h0.y, un[1], Anh);
        Ar = fmaf(h0.z, ur[2], Ar);  Az = fmaf(h0.z, uz[2], Az);  Anh = fmaf(h0.z, un[2], Anh);
        Ar = fmaf(h0.w, ur[3], Ar);  Az = fmaf(h0.w, uz[3], Az);  Anh = fmaf(h0.w, un[3], Anh);
        Ar = fmaf(h1.x, ur[4], Ar);  Az = fmaf(h1.x, uz[4], Az);  Anh = fmaf(h1.x, un[4], Anh);
        Ar = fmaf(h1.y, ur[5], Ar);  Az = fmaf(h1.y, uz[5], Az);  Anh = fmaf(h1.y, un[5], Anh);
        Ar = fmaf(h1.z, ur[6], Ar);  Az = fmaf(h1.z, uz[6], Az);  Anh = fmaf(h1.z, un[6], Anh);
        Ar = fmaf(h1.w, ur[7], Ar);  Az = fmaf(h1.w, uz[7], Az);  Anh = fmaf(h1.w, un[7], Anh);
        Ar = fmaf(h2.x, ur[8], Ar);  Az = fmaf(h2.x, uz[8], Az);  Anh = fmaf(h2.x, un[8], Anh);
        Ar = fmaf(h2.y, ur[9], Ar);  Az = fmaf(h2.y, uz[9], Az);  Anh = fmaf(h2.y, un[9], Anh);
        Ar = fmaf(h2.z, ur[10], Ar); Az = fmaf(h2.z, uz[10], Az); Anh = fmaf(h2.z, un[10], Anh);
        Ar = fmaf(h2.w, ur[11], Ar); Az = fmaf(h2.w, uz[11], Az); Anh = fmaf(h2.w, un[11], Anh);
        Ar = fmaf(h3.x, ur[12], Ar); Az = fmaf(h3.x, uz[12], Az); Anh = fmaf(h3.x, un[12], Anh);
        Ar = fmaf(h3.y, ur[13], Ar); Az = fmaf(h3.y, uz[13], Az); Anh = fmaf(h3.y, un[13], Anh);
        Ar = fmaf(h3.z, ur[14], Ar); Az = fmaf(h3.z, uz[14], Az); Anh = fmaf(h3.z, un[14], Anh);
        Ar = fmaf(h3.w, ur[15], Ar); Az = fmaf(h3.w, uz[15], Az); Anh = fmaf(h3.w, un[15], Anh);

        float tr  = bperm(aX, Ar);
        float tz  = bperm(aX, Az);
        float tni = bperm(aX, Ani);
        float tnh = bperm(aX, Anh);
        Ar  += tr;
        Az  += tz;
        Ani += tni;
        Anh += tnh;

        float r = fast_sigmoid(Ar);
        float z = fast_sigmoid(Az);
        float cand = fast_tanh(fmaf(r, Anh, Ani));
        h = (1.f - z) * cand + z * h;

        if (l < 32) lh[wv][l] = h;
        *op = __float2bfloat16(h);

        float e0 = ebias;
        e0 = fmaf(nx0.x, ew[0], e0); e0 = fmaf(nx0.y, ew[1], e0);
        e0 = fmaf(nx0.z, ew[2], e0); e0 = fmaf(nx0.w, ew[3], e0);
        e0 = fmaf(nx1.x, ew[4], e0); e0 = fmaf(nx1.y, ew[5], e0);
        e0 = fmaf(nx1.z, ew[6], e0); e0 = fmaf(nx1.w, ew[7], e0);
        me = fmaxf(e0, 0.f);
        if (l < 16) lme[wv][l] = me;

        xp = np; op += ostep;
    }
    hT[b * 64 + dir * 32 + j] = h;
}

// ---------------------------------------------------------------------------
// s0 kernel (verified). grid 128 x 256. UNCHANGED.
// ---------------------------------------------------------------------------
__global__ __launch_bounds__(256) void s0_kernel(
    const float* __restrict__ hT, const float* __restrict__ act_w, const float* __restrict__ act_b,
    const float* __restrict__ attn_w, const float* __restrict__ x,
    float* __restrict__ s, float* __restrict__ sWs, float* __restrict__ dec_in,
    float* __restrict__ denom)
{
    if (blockIdx.x == 0){
        for (int i = threadIdx.x; i < 24 * 512; i += 256) denom[i] = 0.f;
    }
    int j = threadIdx.x & 31, g = threadIdx.x >> 5;
    int b = blockIdx.x * 8 + g;
    float acc = act_b[j];
    const float4* aw = (const float4*)(act_w + j * 64);
    const float4* hp = (const float4*)(hT + b * 64);
#pragma unroll
    for (int c = 0; c < 16; c++){
        float4 wv = aw[c]; float4 hv = hp[c];
        acc = fmaf(hv.x, wv.x, acc); acc = fmaf(hv.y, wv.y, acc);
        acc = fmaf(hv.z, wv.z, acc); acc = fmaf(hv.w, wv.w, acc);
    }
    float s0v = fast_tanh(acc);
    s[b * 32 + j] = s0v;
    __shared__ float ssh[8][33];
    ssh[g][j] = s0v;
    __syncthreads();
    float a = 0.f;
    const float4* wsp = (const float4*)(attn_w + j * 96);   // Ws = attn_w[:, :32]
#pragma unroll
    for (int c = 0; c < 8; c++){
        float4 wv = wsp[c];
        a = fmaf(ssh[g][4 * c + 0], wv.x, a);
        a = fmaf(ssh[g][4 * c + 1], wv.y, a);
        a = fmaf(ssh[g][4 * c + 2], wv.z, a);
        a = fmaf(ssh[g][4 * c + 3], wv.w, a);
    }
    sWs[b * 32 + j] = a;
    if (j == 0) dec_in[b] = x[(size_t)b * 4096 + 511 * 8];
}

// ---------------------------------------------------------------------------
// proj kernel (verified). grid 2048 x 256. UNCHANGED.
// ---------------------------------------------------------------------------
__global__ __launch_bounds__(256) void proj_kernel(
    const __hip_bfloat16* __restrict__ enc_outT, const float* __restrict__ attn_w,
    __hip_bfloat16* __restrict__ proj)
{
    int j = threadIdx.x & 31, g = threadIdx.x >> 5;
    float w[64];
    const float4* aw = (const float4*)(attn_w + j * 96 + 32);
#pragma unroll
    for (int c = 0; c < 16; c++){
        float4 q = aw[c];
        w[4 * c] = q.x; w[4 * c + 1] = q.y; w[4 * c + 2] = q.z; w[4 * c + 3] = q.w;
    }
    size_t base = (size_t)blockIdx.x * 256 + g * 32;
    for (int r = 0; r < 32; ++r){
        size_t pl = base + r;                      // pl = b*512 + t
        const uint4* ev = (const uint4*)(enc_outT + pl * 64);
        float acc = 0.f;
#pragma unroll
        for (int c = 0; c < 8; c++){
            uint4 pk = ev[c];
            acc = fmaf(bflo(pk.x), w[8 * c + 0], acc);
            acc = fmaf(bfhi(pk.x), w[8 * c + 1], acc);
            acc = fmaf(bflo(pk.y), w[8 * c + 2], acc);
            acc = fmaf(bfhi(pk.y), w[8 * c + 3], acc);
            acc = fmaf(bflo(pk.z), w[8 * c + 4], acc);
            acc = fmaf(bfhi(pk.z), w[8 * c + 5], acc);
            acc = fmaf(bflo(pk.w), w[8 * c + 6], acc);
            acc = fmaf(bfhi(pk.w), w[8 * c + 7], acc);
        }
        int t = (int)(pl & 511);
        int bb = (int)(pl >> 9);
        proj[((size_t)t * 1024 + bb) * 32 + j] = __float2bfloat16(acc);
    }
}

// ---------------------------------------------------------------------------
// Attention scores v3: each block handles FOUR consecutive t's sharing one
// sWs read. Per-t math, shuffle tree, and per-(t,chunk) partial grouping
// bit-identical to verified R8. grid 512 (= 128 t-quads * 4 b-chunks) x 256.
// ---------------------------------------------------------------------------
__global__ __launch_bounds__(256) void attn_kernel(
    const __hip_bfloat16* __restrict__ proj, const float* __restrict__ sWs,
    const float* __restrict__ attn_v, float* __restrict__ Ebuf, float* __restrict__ denom)
{
    int tq = (blockIdx.x >> 2) * 4;
    int b = (blockIdx.x & 3) * 256 + threadIdx.x;
    float v[32];
    {
        const float4* vv = (const float4*)attn_v;
#pragma unroll
        for (int c = 0; c < 8; c++){
            float4 q = vv[c];
            v[4 * c] = q.x; v[4 * c + 1] = q.y; v[4 * c + 2] = q.z; v[4 * c + 3] = q.w;
        }
    }
    float sv[32];
    {
        const float4* sp = (const float4*)(sWs + b * 32);
#pragma unroll
        for (int c = 0; c < 8; c++){
            float4 q = sp[c];
            sv[4 * c] = q.x; sv[4 * c + 1] = q.y; sv[4 * c + 2] = q.z; sv[4 * c + 3] = q.w;
        }
    }
    float Ev[4];
    float r01, r23;   // packed pair reduction regs (per-t trees kept separate)
    float rr[4];
#pragma unroll
    for (int u = 0; u < 4; ++u){
        const uint4* pp = (const uint4*)(proj + ((size_t)(tq + u) * 1024 + b) * 32);
        float acc = 0.f;
#pragma unroll
        for (int c = 0; c < 4; c++){
            uint4 pk = pp[c];
            acc = fmaf(v[8 * c + 0], fast_tanh(sv[8 * c + 0] + bflo(pk.x)), acc);
            acc = fmaf(v[8 * c + 1], fast_tanh(sv[8 * c + 1] + bfhi(pk.x)), acc);
            acc = fmaf(v[8 * c + 2], fast_tanh(sv[8 * c + 2] + bflo(pk.y)), acc);
            acc = fmaf(v[8 * c + 3], fast_tanh(sv[8 * c + 3] + bfhi(pk.y)), acc);
            acc = fmaf(v[8 * c + 4], fast_tanh(sv[8 * c + 4] + bflo(pk.z)), acc);
            acc = fmaf(v[8 * c + 5], fast_tanh(sv[8 * c + 5] + bfhi(pk.z)), acc);
            acc = fmaf(v[8 * c + 6], fast_tanh(sv[8 * c + 6] + bflo(pk.w)), acc);
            acc = fmaf(v[8 * c + 7], fast_tanh(sv[8 * c + 7] + bfhi(pk.w)), acc);
        }
        Ev[u] = __builtin_amdgcn_exp2f(LOG2E * acc);
        Ebuf[(size_t)(tq + u) * 1024 + b] = Ev[u];
        rr[u] = Ev[u];
    }
    (void)r01; (void)r23;
#pragma unroll
    for (int o = 32; o >= 1; o >>= 1){
        rr[0] += __shfl_xor(rr[0], o, 64);
        rr[1] += __shfl_xor(rr[1], o, 64);
        rr[2] += __shfl_xor(rr[2], o, 64);
        rr[3] += __shfl_xor(rr[3], o, 64);
    }
    __shared__ float wsum[4][4];    // [t][wave]
    if ((threadIdx.x & 63) == 0){
        int wvi = threadIdx.x >> 6;
        wsum[0][wvi] = rr[0]; wsum[1][wvi] = rr[1];
        wsum[2][wvi] = rr[2]; wsum[3][wvi] = rr[3];
    }
    __syncthreads();
    if (threadIdx.x == 0){
#pragma unroll
        for (int u = 0; u < 4; ++u)
            atomicAdd(denom + tq + u, wsum[u][0] + wsum[u][1] + wsum[u][2] + wsum[u][3]);
    }
}

// ---------------------------------------------------------------------------
// Decoder step v3: each block handles TWO adjacent b's (b0=2*bid, b1=2*bid+1).
// Ebuf columns read as float2 (adjacent), denom shared; GRU/tail for b1 runs
// concurrently on threads 96..191 / wave 2 (previously idle). Per-b chains
// verbatim from verified R8. grid 512 x 256.
// ---------------------------------------------------------------------------
__global__ __launch_bounds__(256) void dec_kernel(
    const __hip_bfloat16* __restrict__ enc_outT, const float* __restrict__ Ebuf,
    const float* __restrict__ denom, float* __restrict__ s, float* __restrict__ sWs,
    float* __restrict__ dec_in,
    const float* __restrict__ demb_w, const float* __restrict__ demb_b,
    const float* __restrict__ dwih, const float* __restrict__ dwhh,
    const float* __restrict__ dbih, const float* __restrict__ dbhh,
    const float* __restrict__ attn_w, const float* __restrict__ fc_w,
    const float* __restrict__ fc_b, float* __restrict__ out, int step)
{
    __shared__ float w_sh0[512], w_sh1[512];
    __shared__ float ctxp0[4][64], ctxp1[4][64];
    __shared__ float rnn0[80], rnn1[80];      // [embd(16), ctx(64)]
    __shared__ float scur0[32], scur1[32];
    __shared__ float gsum0[64], gsum1[64];
    __shared__ float gin0[32], ghn0[32], gin1[32], ghn1[32];
    __shared__ float snew0[32], snew1[32];
    int tid = threadIdx.x;
    int b0 = blockIdx.x * 2;
    int b1 = b0 + 1;
    int wv = tid >> 6, l = tid & 63;

    // softmax weights for both b's: adjacent columns -> float2 loads
    {
        float d0 = denom[tid], d1 = denom[tid + 256];
        float2 eA = *(const float2*)(Ebuf + (size_t)tid * 1024 + b0);
        float2 eB = *(const float2*)(Ebuf + (size_t)(tid + 256) * 1024 + b0);
        float rc0 = __builtin_amdgcn_rcpf(d0);
        float rc1 = __builtin_amdgcn_rcpf(d1);
        w_sh0[tid] = eA.x * rc0;  w_sh1[tid] = eA.y * rc0;
        w_sh0[tid + 256] = eB.x * rc1;  w_sh1[tid + 256] = eB.y * rc1;
    }
    if (tid < 16)              rnn0[tid]      = fmaxf(fmaf(dec_in[b0], demb_w[tid],      demb_b[tid]), 0.f);
    else if (tid < 32)         rnn1[tid - 16] = fmaxf(fmaf(dec_in[b1], demb_w[tid - 16], demb_b[tid - 16]), 0.f);
    else if (tid < 64)         scur0[tid - 32] = s[b0 * 32 + tid - 32];
    else if (tid < 96)         scur1[tid - 64] = s[b1 * 32 + tid - 64];
    __syncthreads();

    // ctx sweeps: b0 then b1 (identical per-b math to R8)
#pragma unroll
    for (int pass = 0; pass < 2; ++pass){
        int bb = pass ? b1 : b0;
        const float* wsh = pass ? w_sh1 : w_sh0;
        float acc0 = 0.f, acc1 = 0.f, acc2 = 0.f, acc3 = 0.f;
        float acc4 = 0.f, acc5 = 0.f, acc6 = 0.f, acc7 = 0.f;
        const uint4* ep = (const uint4*)(enc_outT + (size_t)bb * 32768);
#pragma unroll
        for (int i = 0; i < 16; i++){
            int idx = i * 256 + tid;
            uint4 pk = ep[idx];
            float wgt = wsh[idx >> 3];
            acc0 = fmaf(wgt, bflo(pk.x), acc0);
            acc1 = fmaf(wgt, bfhi(pk.x), acc1);
            acc2 = fmaf(wgt, bflo(pk.y), acc2);
            acc3 = fmaf(wgt, bfhi(pk.y), acc3);
            acc4 = fmaf(wgt, bflo(pk.z), acc4);
            acc5 = fmaf(wgt, bfhi(pk.z), acc5);
            acc6 = fmaf(wgt, bflo(pk.w), acc6);
            acc7 = fmaf(wgt, bfhi(pk.w), acc7);
        }
#pragma unroll
        for (int o = 8; o <= 32; o <<= 1){
            acc0 += __shfl_xor(acc0, o, 64); acc1 += __shfl_xor(acc1, o, 64);
            acc2 += __shfl_xor(acc2, o, 64); acc3 += __shfl_xor(acc3, o, 64);
            acc4 += __shfl_xor(acc4, o, 64); acc5 += __shfl_xor(acc5, o, 64);
            acc6 += __shfl_xor(acc6, o, 64); acc7 += __shfl_xor(acc7, o, 64);
        }
        if (l < 8){
            float* cp = pass ? &ctxp1[wv][l * 8] : &ctxp0[wv][l * 8];
            cp[0] = acc0; cp[1] = acc1; cp[2] = acc2; cp[3] = acc3;
            cp[4] = acc4; cp[5] = acc5; cp[6] = acc6; cp[7] = acc7;
        }
    }
    __syncthreads();
    if (tid < 64)       rnn0[16 + tid]        = ctxp0[0][tid] + ctxp0[1][tid] + ctxp0[2][tid] + ctxp0[3][tid];
    else if (tid < 128) rnn1[16 + (tid - 64)] = ctxp1[0][tid - 64] + ctxp1[1][tid - 64] + ctxp1[2][tid - 64] + ctxp1[3][tid - 64];
    __syncthreads();

    // GRU GEMV: b0 rows on tid 0..95, b1 rows on tid 96..191 (concurrent)
    if (tid < 192){
        int pass = tid >= 96;
        int row = pass ? tid - 96 : tid;
        const float* rnnS  = pass ? rnn1 : rnn0;
        const float* scurS = pass ? scur1 : scur0;
        float gi = dbih[row];
        const float4* wr = (const float4*)(dwih + row * 80);
#pragma unroll
        for (int c = 0; c < 20; c++){
            float4 wv4 = wr[c];
            gi = fmaf(rnnS[4 * c + 0], wv4.x, gi);
            gi = fmaf(rnnS[4 * c + 1], wv4.y, gi);
            gi = fmaf(rnnS[4 * c + 2], wv4.z, gi);
            gi = fmaf(rnnS[4 * c + 3], wv4.w, gi);
        }
        float gh = dbhh[row];
        const float4* urow = (const float4*)(dwhh + row * 32);
#pragma unroll
        for (int c = 0; c < 8; c++){
            float4 wv4 = urow[c];
            gh = fmaf(scurS[4 * c + 0], wv4.x, gh);
            gh = fmaf(scurS[4 * c + 1], wv4.y, gh);
            gh = fmaf(scurS[4 * c + 2], wv4.z, gh);
            gh = fmaf(scurS[4 * c + 3], wv4.w, gh);
        }
        if (row < 64){ if (pass) gsum1[row] = gi + gh; else gsum0[row] = gi + gh; }
        else {
            if (pass){ gin1[row - 64] = gi; ghn1[row - 64] = gh; }
            else     { gin0[row - 64] = gi; ghn0[row - 64] = gh; }
        }
    }
    __syncthreads();

    if (tid < 32){
        float r = fast_sigmoid(gsum0[tid]);
        float z = fast_sigmoid(gsum0[32 + tid]);
        float cand = fast_tanh(fmaf(r, ghn0[tid], gin0[tid]));
        float sn = (1.f - z) * cand + z * scur0[tid];
        snew0[tid] = sn;
        s[b0 * 32 + tid] = sn;
    } else if (tid < 64){
        int jj = tid - 32;
        float r = fast_sigmoid(gsum1[jj]);
        float z = fast_sigmoid(gsum1[32 + jj]);
        float cand = fast_tanh(fmaf(r, ghn1[jj], gin1[jj]));
        float sn = (1.f - z) * cand + z * scur1[jj];
        snew1[jj] = sn;
        s[b1 * 32 + jj] = sn;
    }
    __syncthreads();

    if (tid < 32){   // next-step sWs for b0
        float a = 0.f;
        const float4* aw = (const float4*)(attn_w + tid * 96);
#pragma unroll
        for (int c = 0; c < 8; c++){
            float4 wv4 = aw[c];
            a = fmaf(snew0[4 * c + 0], wv4.x, a);
            a = fmaf(snew0[4 * c + 1], wv4.y, a);
            a = fmaf(snew0[4 * c + 2], wv4.z, a);
            a = fmaf(snew0[4 * c + 3], wv4.w, a);
        }
        sWs[b0 * 32 + tid] = a;
    } else if (tid < 64){   // next-step sWs for b1
        int jj = tid - 32;
        float a = 0.f;
        const float4* aw = (const float4*)(attn_w + jj * 96);
#pragma unroll
        for (int c = 0; c < 8; c++){
            float4 wv4 = aw[c];
            a = fmaf(snew1[4 * c + 0], wv4.x, a);
            a = fmaf(snew1[4 * c + 1], wv4.y, a);
            a = fmaf(snew1[4 * c + 2], wv4.z, a);
            a = fmaf(snew1[4 * c + 3], wv4.w, a);
        }
        sWs[b1 * 32 + jj] = a;
    } else if (tid < 128){   // fc for b0 on wave 1
        int ll = tid - 64;
        float cv0 = (ll < 32) ? snew0[ll] : rnn0[ll - 16];
        float p = cv0 * fc_w[ll];
        if (ll < 48){
            int i = 64 + ll;
            float cv1 = (i < 96) ? rnn0[i - 16] : rnn0[i - 96];
            p = fmaf(cv1, fc_w[i], p);
        }
#pragma unroll
        for (int o = 32; o >= 1; o >>= 1) p += __shfl_xor(p, o, 64);
        if (ll == 0){
            float pred = p + fc_b[0];
            out[b0 * 24 + step] = pred;
            dec_in[b0] = pred;
        }
    } else if (tid < 192){   // fc for b1 on wave 2
        int ll = tid - 128;
        float cv0 = (ll < 32) ? snew1[ll] : rnn1[ll - 16];
        float p = cv0 * fc_w[ll];
        if (ll < 48){
            int i = 64 + ll;
            float cv1 = (i < 96) ? rnn1[i - 16] : rnn1[i - 96];
            p = fmaf(cv1, fc_w[i], p);
        }
#pragma unroll
        for (int o = 32; o >= 1; o >>= 1) p += __shfl_xor(p, o, 64);
        if (ll == 0){
            float pred = p + fc_b[0];
            out[b1 * 24 + step] = pred;
            dec_in[b1] = pred;
        }
    }
}

// ---------------------------------------------------------------------------
extern "C" void kernel_launch(void* const* d_in, const int* in_sizes, int n_in,
                              void* d_out, int out_size, void* d_ws, size_t ws_size,
                              hipStream_t stream)
{
    const float* x      = (const float*)d_in[0];
    const float* emb_w  = (const float*)d_in[2];
    const float* emb_b  = (const float*)d_in[3];
    const float* wih_f  = (const float*)d_in[4];
    const float* whh_f  = (const float*)d_in[5];
    const float* bih_f  = (const float*)d_in[6];
    const float* bhh_f  = (const float*)d_in[7];
    const float* wih_b  = (const float*)d_in[8];
    const float* whh_b  = (const float*)d_in[9];
    const float* bih_b  = (const float*)d_in[10];
    const float* bhh_b  = (const float*)d_in[11];
    const float* act_w  = (const float*)d_in[12];
    const float* act_b  = (const float*)d_in[13];
    const float* attn_w = (const float*)d_in[14];
    const float* attn_v = (const float*)d_in[15];
    const float* demb_w = (const float*)d_in[16];
    const float* demb_b = (const float*)d_in[17];
    const float* dwih   = (const float*)d_in[18];
    const float* dwhh   = (const float*)d_in[19];
    const float* dbih   = (const float*)d_in[20];
    const float* dbhh   = (const float*)d_in[21];
    const float* fc_w   = (const float*)d_in[22];
    const float* fc_b   = (const float*)d_in[23];
    (void)in_sizes; (void)n_in; (void)out_size; (void)ws_size;

    char* w = (char*)d_ws;
    __hip_bfloat16* enc_outT = (__hip_bfloat16*)w;                // [b][t][64] bf16, 67108864 B
    __hip_bfloat16* proj     = (__hip_bfloat16*)(w + 67108864);   // [t][b][32] bf16, 33554432 B
    float* hT     = (float*)(w + 100663296);                      // 1024*64*4
    float* s      = (float*)(w + 100925440);                      // 1024*32*4
    float* sWs    = (float*)(w + 101056512);                      // 1024*32*4
    float* Ebuf   = (float*)(w + 101187584);                      // [t][b] f32, 2097152 B
    float* denom  = (float*)(w + 103284736);                      // 24*512*4
    float* dec_in = (float*)(w + 103333888);                      // 1024*4
    float* out = (float*)d_out;

    enc_kernel<<<512, 256, 0, stream>>>(x, emb_w, emb_b, wih_f, whh_f, bih_f, bhh_f,
                                        wih_b, whh_b, bih_b, bhh_b, enc_outT, hT);
    s0_kernel<<<128, 256, 0, stream>>>(hT, act_w, act_b, attn_w, x, s, sWs, dec_in, denom);
    proj_kernel<<<2048, 256, 0, stream>>>(enc_outT, attn_w, proj);
    for (int st = 0; st < 24; ++st){
        attn_kernel<<<512, 256, 0, stream>>>(proj, sWs, attn_v, Ebuf, denom + st * 512);
        dec_kernel<<<512, 256, 0, stream>>>(enc_outT, Ebuf, denom + st * 512, s, sWs, dec_in,
                                            demb_w, demb_b, dwih, dwhh, dbih, dbhh,
                                            attn_w, fc_w, fc_b, out, st);
    }
}

// Round 10
// 1098.080 us; speedup vs baseline: 5.3657x; 1.0075x over previous
//
#include <hip/hip_runtime.h>
#include <hip/hip_bf16.h>
#include <stdint.h>
#include <stddef.h>

// Problem dims: B=1024, T=512, F=8, E=16, H=32, O=1, TO=24

#define LOG2E 1.44269504088896340736f

__device__ __forceinline__ float fast_sigmoid(float x){
    return __builtin_amdgcn_rcpf(1.f + __builtin_amdgcn_exp2f(-LOG2E * x));
}
__device__ __forceinline__ float fast_tanh(float x){
    return 1.f - 2.f * __builtin_amdgcn_rcpf(1.f + __builtin_amdgcn_exp2f(2.f * LOG2E * x));
}
__device__ __forceinline__ float bflo(unsigned u){ return __uint_as_float(u << 16); }
__device__ __forceinline__ float bfhi(unsigned u){ return __uint_as_float(u & 0xffff0000u); }
__device__ __forceinline__ float bperm(int addr, float v){
    return __int_as_float(__builtin_amdgcn_ds_bpermute(addr, __float_as_int(v)));
}

// ---------------------------------------------------------------------------
// Encoder: bidirectional GRU, ONE WAVE per sequence. (R3 verified: 254 µs,
// VALUBusy 84%.) Batched ds_read_b128 broadcasts + ds_bpermute half-combine.
// grid 512 x 256 (4 seqs/block, 2048 waves = 2 waves/SIMD). UNCHANGED.
// ---------------------------------------------------------------------------
__global__ __launch_bounds__(256, 2) void enc_kernel(
    const float* __restrict__ x,
    const float* __restrict__ emb_w, const float* __restrict__ emb_b,
    const float* __restrict__ wih_f, const float* __restrict__ whh_f,
    const float* __restrict__ bih_f, const float* __restrict__ bhh_f,
    const float* __restrict__ wih_b, const float* __restrict__ whh_b,
    const float* __restrict__ bih_b, const float* __restrict__ bhh_b,
    __hip_bfloat16* __restrict__ enc_outT, float* __restrict__ hT)
{
    __shared__ float lme[4][16];
    __shared__ float lh[4][32];

    int tid = threadIdx.x;
    int l = tid & 63;
    int wv = tid >> 6;
    int j = l & 31;
    int p = l >> 5;
    int S = blockIdx.x * 4 + wv;        // 0..2047
    int dir = S >> 10;
    int b = S & 1023;
    const float* wih = dir ? wih_b : wih_f;
    const float* whh = dir ? whh_b : whh_f;
    const float* bih = dir ? bih_b : bih_f;
    const float* bhh = dir ? bhh_b : bhh_f;

    float wr[8], wz[8], wn[8];
#pragma unroll
    for (int e = 0; e < 8; e++){
        int ee = 8 * p + e;
        wr[e] = wih[j * 16 + ee];
        wz[e] = wih[(32 + j) * 16 + ee];
        wn[e] = wih[(64 + j) * 16 + ee];
    }
    float ur[16], uz[16], un[16];
#pragma unroll
    for (int k = 0; k < 16; k++){
        int kk = 16 * p + k;
        ur[k] = whh[j * 32 + kk];
        uz[k] = whh[(32 + j) * 32 + kk];
        un[k] = whh[(64 + j) * 32 + kk];
    }
    float c_r  = p ? 0.f : (bih[j] + bhh[j]);
    float c_z  = p ? 0.f : (bih[32 + j] + bhh[32 + j]);
    float c_ni = p ? 0.f : bih[64 + j];
    float c_nh = p ? 0.f : bhh[64 + j];

    float ew[8];
#pragma unroll
    for (int f = 0; f < 8; f++) ew[f] = emb_w[(l & 15) * 8 + f];
    float ebias = emb_b[l & 15];

    int aX = 4 * (l ^ 32);

    float h = 0.f;
    const float* xp = x + (size_t)b * 4096 + (dir ? 511 * 8 : 0);
    __hip_bfloat16* op = enc_outT + ((size_t)b * 512 + (dir ? 511 : 0)) * 64 + dir * 32 + j;
    int xstep = dir ? -8 : 8;
    ptrdiff_t ostep = dir ? -64 : 64;

    float4 cx0 = ((const float4*)xp)[0];
    float4 cx1 = ((const float4*)xp)[1];

    float me;
    {
        float e0 = ebias;
        e0 = fmaf(cx0.x, ew[0], e0); e0 = fmaf(cx0.y, ew[1], e0);
        e0 = fmaf(cx0.z, ew[2], e0); e0 = fmaf(cx0.w, ew[3], e0);
        e0 = fmaf(cx1.x, ew[4], e0); e0 = fmaf(cx1.y, ew[5], e0);
        e0 = fmaf(cx1.z, ew[6], e0); e0 = fmaf(cx1.w, ew[7], e0);
        me = fmaxf(e0, 0.f);
    }
    if (l < 16) lme[wv][l] = me;
    if (l < 32) lh[wv][l] = h;

    const float4* pe = (const float4*)(&lme[wv][8 * p]);
    const float4* ph = (const float4*)(&lh[wv][16 * p]);

    for (int it = 0; it < 512; ++it){
        const float* np = (it == 511) ? xp : (xp + xstep);
        float4 nx0 = ((const float4*)np)[0];
        float4 nx1 = ((const float4*)np)[1];

        float4 e01 = pe[0], e23 = pe[1];
        float4 h0 = ph[0], h1 = ph[1], h2 = ph[2], h3 = ph[3];

        float Ar = c_r, Az = c_z, Ani = c_ni, Anh = c_nh;

        Ar = fmaf(e01.x, wr[0], Ar); Az = fmaf(e01.x, wz[0], Az); Ani = fmaf(e01.x, wn[0], Ani);
        Ar = fmaf(e01.y, wr[1], Ar); Az = fmaf(e01.y, wz[1], Az); Ani = fmaf(e01.y, wn[1], Ani);
        Ar = fmaf(e01.z, wr[2], Ar); Az = fmaf(e01.z, wz[2], Az); Ani = fmaf(e01.z, wn[2], Ani);
        Ar = fmaf(e01.w, wr[3], Ar); Az = fmaf(e01.w, wz[3], Az); Ani = fmaf(e01.w, wn[3], Ani);
        Ar = fmaf(e23.x, wr[4], Ar); Az = fmaf(e23.x, wz[4], Az); Ani = fmaf(e23.x, wn[4], Ani);
        Ar = fmaf(e23.y, wr[5], Ar); Az = fmaf(e23.y, wz[5], Az); Ani = fmaf(e23.y, wn[5], Ani);
        Ar = fmaf(e23.z, wr[6], Ar); Az = fmaf(e23.z, wz[6], Az); Ani = fmaf(e23.z, wn[6], Ani);
        Ar = fmaf(e23.w, wr[7], Ar); Az = fmaf(e23.w, wz[7], Az); Ani = fmaf(e23.w, wn[7], Ani);

        Ar = fmaf(h0.x, ur[0], Ar);  Az = fmaf(h0.x, uz[0], Az);  Anh = fmaf(h0.x, un[0], Anh);
        Ar = fmaf(h0.y, ur[1], Ar);  Az = fmaf(h0.y, uz[1], Az);  Anh = fmaf(h0.y, un[1], Anh);
        Ar = fmaf(h0.z, ur[2], Ar);  Az = fmaf(h0.z, uz[2], Az);  Anh = fmaf(h0.z, un[2], Anh);
        Ar = fmaf(h0.w, ur[3], Ar);  Az = fmaf(h0.w, uz[3], Az);  Anh = fmaf(h0.w, un[3], Anh);
        Ar = fmaf(h1.x, ur[4], Ar);  Az = fmaf(h1.x, uz[4], Az);  Anh = fmaf(h1.x, un[4], Anh);
        Ar = fmaf(h1.y, ur[5], Ar);  Az = fmaf(h1.y, uz[5], Az);  Anh = fmaf(h1.y, un[5], Anh);
        Ar = fmaf(h1.z, ur[6], Ar);  Az = fmaf(h1.z, uz[6], Az);  Anh = fmaf(h1.z, un[6], Anh);
        Ar = fmaf(h1.w, ur[7], Ar);  Az = fmaf(h1.w, uz[7], Az);  Anh = fmaf(h1.w, un[7], Anh);
        Ar = fmaf(h2.x, ur[8], Ar);  Az = fmaf(h2.x, uz[8], Az);  Anh = fmaf(h2.x, un[8], Anh);
        Ar = fmaf(h2.y, ur[9], Ar);  Az = fmaf(h2.y, uz[9], Az);  Anh = fmaf(h2.y, un[9], Anh);
        Ar = fmaf(h2.z, ur[10], Ar); Az = fmaf(h2.z, uz[10], Az); Anh = fmaf(h2.z, un[10], Anh);
        Ar = fmaf(h2.w, ur[11], Ar); Az = fmaf(h2.w, uz[11], Az); Anh = fmaf(h2.w, un[11], Anh);
        Ar = fmaf(h3.x, ur[12], Ar); Az = fmaf(h3.x, uz[12], Az); Anh = fmaf(h3.x, un[12], Anh);
        Ar = fmaf(h3.y, ur[13], Ar); Az = fmaf(h3.y, uz[13], Az); Anh = fmaf(h3.y, un[13], Anh);
        Ar = fmaf(h3.z, ur[14], Ar); Az = fmaf(h3.z, uz[14], Az); Anh = fmaf(h3.z, un[14], Anh);
        Ar = fmaf(h3.w, ur[15], Ar); Az = fmaf(h3.w, uz[15], Az); Anh = fmaf(h3.w, un[15], Anh);

        float tr  = bperm(aX, Ar);
        float tz  = bperm(aX, Az);
        float tni = bperm(aX, Ani);
        float tnh = bperm(aX, Anh);
        Ar  += tr;
        Az  += tz;
        Ani += tni;
        Anh += tnh;

        float r = fast_sigmoid(Ar);
        float z = fast_sigmoid(Az);
        float cand = fast_tanh(fmaf(r, Anh, Ani));
        h = (1.f - z) * cand + z * h;

        if (l < 32) lh[wv][l] = h;
        *op = __float2bfloat16(h);

        float e0 = ebias;
        e0 = fmaf(nx0.x, ew[0], e0); e0 = fmaf(nx0.y, ew[1], e0);
        e0 = fmaf(nx0.z, ew[2], e0); e0 = fmaf(nx0.w, ew[3], e0);
        e0 = fmaf(nx1.x, ew[4], e0); e0 = fmaf(nx1.y, ew[5], e0);
        e0 = fmaf(nx1.z, ew[6], e0); e0 = fmaf(nx1.w, ew[7], e0);
        me = fmaxf(e0, 0.f);
        if (l < 16) lme[wv][l] = me;

        xp = np; op += ostep;
    }
    hT[b * 64 + dir * 32 + j] = h;
}

// ---------------------------------------------------------------------------
// s0 kernel (verified). grid 128 x 256. UNCHANGED.
// ---------------------------------------------------------------------------
__global__ __launch_bounds__(256) void s0_kernel(
    const float* __restrict__ hT, const float* __restrict__ act_w, const float* __restrict__ act_b,
    const float* __restrict__ attn_w, const float* __restrict__ x,
    float* __restrict__ s, float* __restrict__ sWs, float* __restrict__ dec_in,
    float* __restrict__ denom)
{
    if (blockIdx.x == 0){
        for (int i = threadIdx.x; i < 24 * 512; i += 256) denom[i] = 0.f;
    }
    int j = threadIdx.x & 31, g = threadIdx.x >> 5;
    int b = blockIdx.x * 8 + g;
    float acc = act_b[j];
    const float4* aw = (const float4*)(act_w + j * 64);
    const float4* hp = (const float4*)(hT + b * 64);
#pragma unroll
    for (int c = 0; c < 16; c++){
        float4 wv = aw[c]; float4 hv = hp[c];
        acc = fmaf(hv.x, wv.x, acc); acc = fmaf(hv.y, wv.y, acc);
        acc = fmaf(hv.z, wv.z, acc); acc = fmaf(hv.w, wv.w, acc);
    }
    float s0v = fast_tanh(acc);
    s[b * 32 + j] = s0v;
    __shared__ float ssh[8][33];
    ssh[g][j] = s0v;
    __syncthreads();
    float a = 0.f;
    const float4* wsp = (const float4*)(attn_w + j * 96);   // Ws = attn_w[:, :32]
#pragma unroll
    for (int c = 0; c < 8; c++){
        float4 wv = wsp[c];
        a = fmaf(ssh[g][4 * c + 0], wv.x, a);
        a = fmaf(ssh[g][4 * c + 1], wv.y, a);
        a = fmaf(ssh[g][4 * c + 2], wv.z, a);
        a = fmaf(ssh[g][4 * c + 3], wv.w, a);
    }
    sWs[b * 32 + j] = a;
    if (j == 0) dec_in[b] = x[(size_t)b * 4096 + 511 * 8];
}

// ---------------------------------------------------------------------------
// proj kernel (verified). grid 2048 x 256. UNCHANGED.
// ---------------------------------------------------------------------------
__global__ __launch_bounds__(256) void proj_kernel(
    const __hip_bfloat16* __restrict__ enc_outT, const float* __restrict__ attn_w,
    __hip_bfloat16* __restrict__ proj)
{
    int j = threadIdx.x & 31, g = threadIdx.x >> 5;
    float w[64];
    const float4* aw = (const float4*)(attn_w + j * 96 + 32);
#pragma unroll
    for (int c = 0; c < 16; c++){
        float4 q = aw[c];
        w[4 * c] = q.x; w[4 * c + 1] = q.y; w[4 * c + 2] = q.z; w[4 * c + 3] = q.w;
    }
    size_t base = (size_t)blockIdx.x * 256 + g * 32;
    for (int r = 0; r < 32; ++r){
        size_t pl = base + r;                      // pl = b*512 + t
        const uint4* ev = (const uint4*)(enc_outT + pl * 64);
        float acc = 0.f;
#pragma unroll
        for (int c = 0; c < 8; c++){
            uint4 pk = ev[c];
            acc = fmaf(bflo(pk.x), w[8 * c + 0], acc);
            acc = fmaf(bfhi(pk.x), w[8 * c + 1], acc);
            acc = fmaf(bflo(pk.y), w[8 * c + 2], acc);
            acc = fmaf(bfhi(pk.y), w[8 * c + 3], acc);
            acc = fmaf(bflo(pk.z), w[8 * c + 4], acc);
            acc = fmaf(bfhi(pk.z), w[8 * c + 5], acc);
            acc = fmaf(bflo(pk.w), w[8 * c + 6], acc);
            acc = fmaf(bfhi(pk.w), w[8 * c + 7], acc);
        }
        int t = (int)(pl & 511);
        int bb = (int)(pl >> 9);
        proj[((size_t)t * 1024 + bb) * 32 + j] = __float2bfloat16(acc);
    }
}

// ---------------------------------------------------------------------------
// Attention scores v3 (R9 verified): FOUR consecutive t's per block sharing
// one sWs read. grid 512 x 256. UNCHANGED.
// ---------------------------------------------------------------------------
__global__ __launch_bounds__(256) void attn_kernel(
    const __hip_bfloat16* __restrict__ proj, const float* __restrict__ sWs,
    const float* __restrict__ attn_v, float* __restrict__ Ebuf, float* __restrict__ denom)
{
    int tq = (blockIdx.x >> 2) * 4;
    int b = (blockIdx.x & 3) * 256 + threadIdx.x;
    float v[32];
    {
        const float4* vv = (const float4*)attn_v;
#pragma unroll
        for (int c = 0; c < 8; c++){
            float4 q = vv[c];
            v[4 * c] = q.x; v[4 * c + 1] = q.y; v[4 * c + 2] = q.z; v[4 * c + 3] = q.w;
        }
    }
    float sv[32];
    {
        const float4* sp = (const float4*)(sWs + b * 32);
#pragma unroll
        for (int c = 0; c < 8; c++){
            float4 q = sp[c];
            sv[4 * c] = q.x; sv[4 * c + 1] = q.y; sv[4 * c + 2] = q.z; sv[4 * c + 3] = q.w;
        }
    }
    float Ev[4];
    float rr[4];
#pragma unroll
    for (int u = 0; u < 4; ++u){
        const uint4* pp = (const uint4*)(proj + ((size_t)(tq + u) * 1024 + b) * 32);
        float acc = 0.f;
#pragma unroll
        for (int c = 0; c < 4; c++){
            uint4 pk = pp[c];
            acc = fmaf(v[8 * c + 0], fast_tanh(sv[8 * c + 0] + bflo(pk.x)), acc);
            acc = fmaf(v[8 * c + 1], fast_tanh(sv[8 * c + 1] + bfhi(pk.x)), acc);
            acc = fmaf(v[8 * c + 2], fast_tanh(sv[8 * c + 2] + bflo(pk.y)), acc);
            acc = fmaf(v[8 * c + 3], fast_tanh(sv[8 * c + 3] + bfhi(pk.y)), acc);
            acc = fmaf(v[8 * c + 4], fast_tanh(sv[8 * c + 4] + bflo(pk.z)), acc);
            acc = fmaf(v[8 * c + 5], fast_tanh(sv[8 * c + 5] + bfhi(pk.z)), acc);
            acc = fmaf(v[8 * c + 6], fast_tanh(sv[8 * c + 6] + bflo(pk.w)), acc);
            acc = fmaf(v[8 * c + 7], fast_tanh(sv[8 * c + 7] + bfhi(pk.w)), acc);
        }
        Ev[u] = __builtin_amdgcn_exp2f(LOG2E * acc);
        Ebuf[(size_t)(tq + u) * 1024 + b] = Ev[u];
        rr[u] = Ev[u];
    }
#pragma unroll
    for (int o = 32; o >= 1; o >>= 1){
        rr[0] += __shfl_xor(rr[0], o, 64);
        rr[1] += __shfl_xor(rr[1], o, 64);
        rr[2] += __shfl_xor(rr[2], o, 64);
        rr[3] += __shfl_xor(rr[3], o, 64);
    }
    __shared__ float wsum[4][4];    // [t][wave]
    if ((threadIdx.x & 63) == 0){
        int wvi = threadIdx.x >> 6;
        wsum[0][wvi] = rr[0]; wsum[1][wvi] = rr[1];
        wsum[2][wvi] = rr[2]; wsum[3][wvi] = rr[3];
    }
    __syncthreads();
    if (threadIdx.x == 0){
#pragma unroll
        for (int u = 0; u < 4; ++u)
            atomicAdd(denom + tq + u, wsum[u][0] + wsum[u][1] + wsum[u][2] + wsum[u][3]);
    }
}

// ---------------------------------------------------------------------------
// Decoder step v4: TWO adjacent b's per block (R9 verified structure) +
// pre-barrier PREFETCH of the first 8 enc_outT chunks of pass 0. The enc
// loads are independent of w_sh; issuing them before __syncthreads (whose
// vmcnt(0) drain already waits on the Ebuf gather) hides their L3 latency
// under the w_sh phase. Load values and fma order bit-identical to R9.
// grid 512 x 256.
// ---------------------------------------------------------------------------
__global__ __launch_bounds__(256) void dec_kernel(
    const __hip_bfloat16* __restrict__ enc_outT, const float* __restrict__ Ebuf,
    const float* __restrict__ denom, float* __restrict__ s, float* __restrict__ sWs,
    float* __restrict__ dec_in,
    const float* __restrict__ demb_w, const float* __restrict__ demb_b,
    const float* __restrict__ dwih, const float* __restrict__ dwhh,
    const float* __restrict__ dbih, const float* __restrict__ dbhh,
    const float* __restrict__ attn_w, const float* __restrict__ fc_w,
    const float* __restrict__ fc_b, float* __restrict__ out, int step)
{
    __shared__ float w_sh0[512], w_sh1[512];
    __shared__ float ctxp0[4][64], ctxp1[4][64];
    __shared__ float rnn0[80], rnn1[80];      // [embd(16), ctx(64)]
    __shared__ float scur0[32], scur1[32];
    __shared__ float gsum0[64], gsum1[64];
    __shared__ float gin0[32], ghn0[32], gin1[32], ghn1[32];
    __shared__ float snew0[32], snew1[32];
    int tid = threadIdx.x;
    int b0 = blockIdx.x * 2;
    int b1 = b0 + 1;
    int wv = tid >> 6, l = tid & 63;

    const uint4* ep0 = (const uint4*)(enc_outT + (size_t)b0 * 32768);
    const uint4* ep1 = (const uint4*)(enc_outT + (size_t)b1 * 32768);

    // softmax weights for both b's: adjacent columns -> float2 loads
    {
        float d0 = denom[tid], d1 = denom[tid + 256];
        float2 eA = *(const float2*)(Ebuf + (size_t)tid * 1024 + b0);
        float2 eB = *(const float2*)(Ebuf + (size_t)(tid + 256) * 1024 + b0);
        float rc0 = __builtin_amdgcn_rcpf(d0);
        float rc1 = __builtin_amdgcn_rcpf(d1);
        w_sh0[tid] = eA.x * rc0;  w_sh1[tid] = eA.y * rc0;
        w_sh0[tid + 256] = eB.x * rc1;  w_sh1[tid + 256] = eB.y * rc1;
    }
    // PREFETCH: first 8 enc chunks of pass 0 (independent of w_sh); their
    // latency overlaps the Ebuf gather + LDS stores before the barrier.
    uint4 pf[8];
#pragma unroll
    for (int i = 0; i < 8; i++) pf[i] = ep0[i * 256 + tid];

    if (tid < 16)              rnn0[tid]      = fmaxf(fmaf(dec_in[b0], demb_w[tid],      demb_b[tid]), 0.f);
    else if (tid < 32)         rnn1[tid - 16] = fmaxf(fmaf(dec_in[b1], demb_w[tid - 16], demb_b[tid - 16]), 0.f);
    else if (tid < 64)         scur0[tid - 32] = s[b0 * 32 + tid - 32];
    else if (tid < 96)         scur1[tid - 64] = s[b1 * 32 + tid - 64];
    __syncthreads();

    // ctx sweeps: b0 (uses prefetched regs for i<8) then b1
#pragma unroll
    for (int pass = 0; pass < 2; ++pass){
        const uint4* ep = pass ? ep1 : ep0;
        const float* wsh = pass ? w_sh1 : w_sh0;
        float acc0 = 0.f, acc1 = 0.f, acc2 = 0.f, acc3 = 0.f;
        float acc4 = 0.f, acc5 = 0.f, acc6 = 0.f, acc7 = 0.f;
#pragma unroll
        for (int i = 0; i < 16; i++){
            int idx = i * 256 + tid;
            uint4 pk = (pass == 0 && i < 8) ? pf[i] : ep[idx];
            float wgt = wsh[idx >> 3];
            acc0 = fmaf(wgt, bflo(pk.x), acc0);
            acc1 = fmaf(wgt, bfhi(pk.x), acc1);
            acc2 = fmaf(wgt, bflo(pk.y), acc2);
            acc3 = fmaf(wgt, bfhi(pk.y), acc3);
            acc4 = fmaf(wgt, bflo(pk.z), acc4);
            acc5 = fmaf(wgt, bfhi(pk.z), acc5);
            acc6 = fmaf(wgt, bflo(pk.w), acc6);
            acc7 = fmaf(wgt, bfhi(pk.w), acc7);
        }
#pragma unroll
        for (int o = 8; o <= 32; o <<= 1){
            acc0 += __shfl_xor(acc0, o, 64); acc1 += __shfl_xor(acc1, o, 64);
            acc2 += __shfl_xor(acc2, o, 64); acc3 += __shfl_xor(acc3, o, 64);
            acc4 += __shfl_xor(acc4, o, 64); acc5 += __shfl_xor(acc5, o, 64);
            acc6 += __shfl_xor(acc6, o, 64); acc7 += __shfl_xor(acc7, o, 64);
        }
        if (l < 8){
            float* cp = pass ? &ctxp1[wv][l * 8] : &ctxp0[wv][l * 8];
            cp[0] = acc0; cp[1] = acc1; cp[2] = acc2; cp[3] = acc3;
            cp[4] = acc4; cp[5] = acc5; cp[6] = acc6; cp[7] = acc7;
        }
    }
    __syncthreads();
    if (tid < 64)       rnn0[16 + tid]        = ctxp0[0][tid] + ctxp0[1][tid] + ctxp0[2][tid] + ctxp0[3][tid];
    else if (tid < 128) rnn1[16 + (tid - 64)] = ctxp1[0][tid - 64] + ctxp1[1][tid - 64] + ctxp1[2][tid - 64] + ctxp1[3][tid - 64];
    __syncthreads();

    // GRU GEMV: b0 rows on tid 0..95, b1 rows on tid 96..191 (concurrent)
    if (tid < 192){
        int pass = tid >= 96;
        int row = pass ? tid - 96 : tid;
        const float* rnnS  = pass ? rnn1 : rnn0;
        const float* scurS = pass ? scur1 : scur0;
        float gi = dbih[row];
        const float4* wr = (const float4*)(dwih + row * 80);
#pragma unroll
        for (int c = 0; c < 20; c++){
            float4 wv4 = wr[c];
            gi = fmaf(rnnS[4 * c + 0], wv4.x, gi);
            gi = fmaf(rnnS[4 * c + 1], wv4.y, gi);
            gi = fmaf(rnnS[4 * c + 2], wv4.z, gi);
            gi = fmaf(rnnS[4 * c + 3], wv4.w, gi);
        }
        float gh = dbhh[row];
        const float4* urow = (const float4*)(dwhh + row * 32);
#pragma unroll
        for (int c = 0; c < 8; c++){
            float4 wv4 = urow[c];
            gh = fmaf(scurS[4 * c + 0], wv4.x, gh);
            gh = fmaf(scurS[4 * c + 1], wv4.y, gh);
            gh = fmaf(scurS[4 * c + 2], wv4.z, gh);
            gh = fmaf(scurS[4 * c + 3], wv4.w, gh);
        }
        if (row < 64){ if (pass) gsum1[row] = gi + gh; else gsum0[row] = gi + gh; }
        else {
            if (pass){ gin1[row - 64] = gi; ghn1[row - 64] = gh; }
            else     { gin0[row - 64] = gi; ghn0[row - 64] = gh; }
        }
    }
    __syncthreads();

    if (tid < 32){
        float r = fast_sigmoid(gsum0[tid]);
        float z = fast_sigmoid(gsum0[32 + tid]);
        float cand = fast_tanh(fmaf(r, ghn0[tid], gin0[tid]));
        float sn = (1.f - z) * cand + z * scur0[tid];
        snew0[tid] = sn;
        s[b0 * 32 + tid] = sn;
    } else if (tid < 64){
        int jj = tid - 32;
        float r = fast_sigmoid(gsum1[jj]);
        float z = fast_sigmoid(gsum1[32 + jj]);
        float cand = fast_tanh(fmaf(r, ghn1[jj], gin1[jj]));
        float sn = (1.f - z) * cand + z * scur1[jj];
        snew1[jj] = sn;
        s[b1 * 32 + jj] = sn;
    }
    __syncthreads();

    if (tid < 32){   // next-step sWs for b0
        float a = 0.f;
        const float4* aw = (const float4*)(attn_w + tid * 96);
#pragma unroll
        for (int c = 0; c < 8; c++){
            float4 wv4 = aw[c];
            a = fmaf(snew0[4 * c + 0], wv4.x, a);
            a = fmaf(snew0[4 * c + 1], wv4.y, a);
            a = fmaf(snew0[4 * c + 2], wv4.z, a);
            a = fmaf(snew0[4 * c + 3], wv4.w, a);
        }
        sWs[b0 * 32 + tid] = a;
    } else if (tid < 64){   // next-step sWs for b1
        int jj = tid - 32;
        float a = 0.f;
        const float4* aw = (const float4*)(attn_w + jj * 96);
#pragma unroll
        for (int c = 0; c < 8; c++){
            float4 wv4 = aw[c];
            a = fmaf(snew1[4 * c + 0], wv4.x, a);
            a = fmaf(snew1[4 * c + 1], wv4.y, a);
            a = fmaf(snew1[4 * c + 2], wv4.z, a);
            a = fmaf(snew1[4 * c + 3], wv4.w, a);
        }
        sWs[b1 * 32 + jj] = a;
    } else if (tid < 128){   // fc for b0 on wave 1
        int ll = tid - 64;
        float cv0 = (ll < 32) ? snew0[ll] : rnn0[ll - 16];
        float p = cv0 * fc_w[ll];
        if (ll < 48){
            int i = 64 + ll;
            float cv1 = (i < 96) ? rnn0[i - 16] : rnn0[i - 96];
            p = fmaf(cv1, fc_w[i], p);
        }
#pragma unroll
        for (int o = 32; o >= 1; o >>= 1) p += __shfl_xor(p, o, 64);
        if (ll == 0){
            float pred = p + fc_b[0];
            out[b0 * 24 + step] = pred;
            dec_in[b0] = pred;
        }
    } else if (tid < 192){   // fc for b1 on wave 2
        int ll = tid - 128;
        float cv0 = (ll < 32) ? snew1[ll] : rnn1[ll - 16];
        float p = cv0 * fc_w[ll];
        if (ll < 48){
            int i = 64 + ll;
            float cv1 = (i < 96) ? rnn1[i - 16] : rnn1[i - 96];
            p = fmaf(cv1, fc_w[i], p);
        }
#pragma unroll
        for (int o = 32; o >= 1; o >>= 1) p += __shfl_xor(p, o, 64);
        if (ll == 0){
            float pred = p + fc_b[0];
            out[b1 * 24 + step] = pred;
            dec_in[b1] = pred;
        }
    }
}

// ---------------------------------------------------------------------------
extern "C" void kernel_launch(void* const* d_in, const int* in_sizes, int n_in,
                              void* d_out, int out_size, void* d_ws, size_t ws_size,
                              hipStream_t stream)
{
    const float* x      = (const float*)d_in[0];
    const float* emb_w  = (const float*)d_in[2];
    const float* emb_b  = (const float*)d_in[3];
    const float* wih_f  = (const float*)d_in[4];
    const float* whh_f  = (const float*)d_in[5];
    const float* bih_f  = (const float*)d_in[6];
    const float* bhh_f  = (const float*)d_in[7];
    const float* wih_b  = (const float*)d_in[8];
    const float* whh_b  = (const float*)d_in[9];
    const float* bih_b  = (const float*)d_in[10];
    const float* bhh_b  = (const float*)d_in[11];
    const float* act_w  = (const float*)d_in[12];
    const float* act_b  = (const float*)d_in[13];
    const float* attn_w = (const float*)d_in[14];
    const float* attn_v = (const float*)d_in[15];
    const float* demb_w = (const float*)d_in[16];
    const float* demb_b = (const float*)d_in[17];
    const float* dwih   = (const float*)d_in[18];
    const float* dwhh   = (const float*)d_in[19];
    const float* dbih   = (const float*)d_in[20];
    const float* dbhh   = (const float*)d_in[21];
    const float* fc_w   = (const float*)d_in[22];
    const float* fc_b   = (const float*)d_in[23];
    (void)in_sizes; (void)n_in; (void)out_size; (void)ws_size;

    char* w = (char*)d_ws;
    __hip_bfloat16* enc_outT = (__hip_bfloat16*)w;                // [b][t][64] bf16, 67108864 B
    __hip_bfloat16* proj     = (__hip_bfloat16*)(w + 67108864);   // [t][b][32] bf16, 33554432 B
    float* hT     = (float*)(w + 100663296);                      // 1024*64*4
    float* s      = (float*)(w + 100925440);                      // 1024*32*4
    float* sWs    = (float*)(w + 101056512);                      // 1024*32*4
    float* Ebuf   = (float*)(w + 101187584);                      // [t][b] f32, 2097152 B
    float* denom  = (float*)(w + 103284736);                      // 24*512*4
    float* dec_in = (float*)(w + 103333888);                      // 1024*4
    float* out = (float*)d_out;

    enc_kernel<<<512, 256, 0, stream>>>(x, emb_w, emb_b, wih_f, whh_f, bih_f, bhh_f,
                                        wih_b, whh_b, bih_b, bhh_b, enc_outT, hT);
    s0_kernel<<<128, 256, 0, stream>>>(hT, act_w, act_b, attn_w, x, s, sWs, dec_in, denom);
    proj_kernel<<<2048, 256, 0, stream>>>(enc_outT, attn_w, proj);
    for (int st = 0; st < 24; ++st){
        attn_kernel<<<512, 256, 0, stream>>>(proj, sWs, attn_v, Ebuf, denom + st * 512);
        dec_kernel<<<512, 256, 0, stream>>>(enc_outT, Ebuf, denom + st * 512, s, sWs, dec_in,
                                            demb_w, demb_b, dwih, dwhh, dbih, dbhh,
                                            attn_w, fc_w, fc_b, out, st);
    }
}